// Round 6
// baseline (390.791 us; speedup 1.0000x reference)
//
#include <hip/hip_runtime.h>
#include <math.h>

#define N_NODES 50000
#define N_EDGES 800000
#define ETOT    (N_EDGES + N_NODES)
#define DH      128
#define NH      4
#define NEG     0.2f
#define LN_EPS  1e-5f
#define NBLK    ((N_NODES + 255) / 256)   // 196 scan blocks
#define LOG2E   1.4426950408889634f

typedef __attribute__((ext_vector_type(8))) short short8;
typedef __attribute__((ext_vector_type(4))) float f32x4;
typedef __attribute__((ext_vector_type(4))) unsigned uint4v;

// ---------- fp32 -> bf16 (RNE) split helpers (scalar, for pack kernel) ----------
__device__ __forceinline__ unsigned short f2bf(float f) {
    unsigned u = __float_as_uint(f);
    u += 0x7FFFu + ((u >> 16) & 1u);
    return (unsigned short)(u >> 16);
}
__device__ __forceinline__ float bf2f(unsigned short h) {
    return __uint_as_float(((unsigned)h) << 16);
}

// packed split: two fp32 -> one u32 of 2 bf16 (hi) + residual u32 (lo)
__device__ __forceinline__ void split_pair(float a, float b, unsigned& hi, unsigned& lo) {
    unsigned h;
    asm("v_cvt_pk_bf16_f32 %0, %1, %2" : "=v"(h) : "v"(a), "v"(b));
    const float ra = a - __uint_as_float(h << 16);
    const float rb = b - __uint_as_float(h & 0xffff0000u);
    unsigned l;
    asm("v_cvt_pk_bf16_f32 %0, %1, %2" : "=v"(l) : "v"(ra), "v"(rb));
    hi = h; lo = l;
}

// ---------- fast exact-GELU (A&S 7.1.26 erf, max err ~1.5e-7) ----------
__device__ __forceinline__ float gelu_exact(float x) {
    const float z  = x * 0.70710678118654752f;
    const float az = fabsf(z);
    const float tt = __builtin_amdgcn_rcpf(fmaf(0.3275911f, az, 1.f));
    float p = fmaf(1.061405429f, tt, -1.453152027f);
    p = fmaf(p, tt, 1.421413741f);
    p = fmaf(p, tt, -0.284496736f);
    p = fmaf(p, tt, 0.254829592f);
    p = p * tt;
    const float ez = exp2f(-(z * z) * LOG2E);
    float er = fmaf(-p, ez, 1.f);
    er = copysignf(er, z);
    return x * fmaf(0.5f, er, 0.5f);
}

// ========== pack 5 weight matrices into MFMA B-fragment order (hi/lo) ==========
__global__ __launch_bounds__(256) void pack_w_kernel(
    const float* __restrict__ W0, const float* __restrict__ W1,
    const float* __restrict__ W2, const float* __restrict__ W3,
    const float* __restrict__ W4,
    short* __restrict__ hi, short* __restrict__ lo)
{
    const int idx = blockIdx.x * 256 + threadIdx.x;   // 0..81919
    const int mat = idx >> 14;
    const int rem = idx & 16383;
    const int t = rem >> 12, c = (rem >> 9) & 7, l = (rem >> 3) & 63, j = rem & 7;
    const int k = t * 32 + (l >> 4) * 8 + j;
    const int n = c * 16 + (l & 15);
    const float* W = (mat == 0) ? W0 : (mat == 1) ? W1 : (mat == 2) ? W2
                   : (mat == 3) ? W3 : W4;
    const float v = W[k * DH + n];
    const unsigned short h = f2bf(v);
    hi[idx] = (short)h;
    lo[idx] = (short)f2bf(v - bf2f(h));
}

// ========== fused dual GEMM: Yl = A@Wl+bl, Yr = A@Wr+br (A read/split ONCE) ==========
#define MTILE 128
__global__ __launch_bounds__(256) void gemm2_mfma_kernel(
    const float* __restrict__ A, int m_rows,
    const short* __restrict__ WhiL, const short* __restrict__ WloL,
    const float* __restrict__ biasL, float* __restrict__ YL,
    const short* __restrict__ WhiR, const short* __restrict__ WloR,
    const float* __restrict__ biasR, float* __restrict__ YR)
{
    const int w    = threadIdx.x >> 6;
    const int lane = threadIdx.x & 63;
    const int rows0 = blockIdx.x * MTILE + w * 32;
    const int g  = lane >> 4;
    const int rl = lane & 15;

    f32x4 accL[2][8], accR[2][8];
    #pragma unroll
    for (int r = 0; r < 2; ++r)
        #pragma unroll
        for (int c = 0; c < 8; ++c) {
            accL[r][c] = (f32x4){0.f, 0.f, 0.f, 0.f};
            accR[r][c] = (f32x4){0.f, 0.f, 0.f, 0.f};
        }

    for (int t = 0; t < 4; ++t) {
        uint4v hw[2], lw[2];
        #pragma unroll
        for (int r = 0; r < 2; ++r) {
            int arow = rows0 + 16 * r + rl;
            arow = (arow < m_rows) ? arow : (m_rows - 1);
            const float* ap = A + (size_t)arow * DH + t * 32 + g * 8;
            const float4 f0 = *(const float4*)ap;
            const float4 f1 = *(const float4*)(ap + 4);
            unsigned h0, l0, h1, l1, h2, l2, h3, l3;
            split_pair(f0.x, f0.y, h0, l0);
            split_pair(f0.z, f0.w, h1, l1);
            split_pair(f1.x, f1.y, h2, l2);
            split_pair(f1.z, f1.w, h3, l3);
            hw[r] = (uint4v){h0, h1, h2, h3};
            lw[r] = (uint4v){l0, l1, l2, l3};
        }
        const short8 ahi0 = __builtin_bit_cast(short8, hw[0]);
        const short8 ahi1 = __builtin_bit_cast(short8, hw[1]);
        const short8 alo0 = __builtin_bit_cast(short8, lw[0]);
        const short8 alo1 = __builtin_bit_cast(short8, lw[1]);

        #pragma unroll
        for (int c = 0; c < 8; ++c) {
            const int fidx = ((t * 8 + c) * 64 + lane) * 8;
            const short8 bhL = *(const short8*)(WhiL + fidx);
            const short8 blL = *(const short8*)(WloL + fidx);
            const short8 bhR = *(const short8*)(WhiR + fidx);
            const short8 blR = *(const short8*)(WloR + fidx);
            accL[0][c] = __builtin_amdgcn_mfma_f32_16x16x32_bf16(ahi0, bhL, accL[0][c], 0, 0, 0);
            accL[1][c] = __builtin_amdgcn_mfma_f32_16x16x32_bf16(ahi1, bhL, accL[1][c], 0, 0, 0);
            accL[0][c] = __builtin_amdgcn_mfma_f32_16x16x32_bf16(alo0, bhL, accL[0][c], 0, 0, 0);
            accL[1][c] = __builtin_amdgcn_mfma_f32_16x16x32_bf16(alo1, bhL, accL[1][c], 0, 0, 0);
            accL[0][c] = __builtin_amdgcn_mfma_f32_16x16x32_bf16(ahi0, blL, accL[0][c], 0, 0, 0);
            accL[1][c] = __builtin_amdgcn_mfma_f32_16x16x32_bf16(ahi1, blL, accL[1][c], 0, 0, 0);
            accR[0][c] = __builtin_amdgcn_mfma_f32_16x16x32_bf16(ahi0, bhR, accR[0][c], 0, 0, 0);
            accR[1][c] = __builtin_amdgcn_mfma_f32_16x16x32_bf16(ahi1, bhR, accR[1][c], 0, 0, 0);
            accR[0][c] = __builtin_amdgcn_mfma_f32_16x16x32_bf16(alo0, bhR, accR[0][c], 0, 0, 0);
            accR[1][c] = __builtin_amdgcn_mfma_f32_16x16x32_bf16(alo1, bhR, accR[1][c], 0, 0, 0);
            accR[0][c] = __builtin_amdgcn_mfma_f32_16x16x32_bf16(ahi0, blR, accR[0][c], 0, 0, 0);
            accR[1][c] = __builtin_amdgcn_mfma_f32_16x16x32_bf16(ahi1, blR, accR[1][c], 0, 0, 0);
        }
    }
    #pragma unroll
    for (int c = 0; c < 8; ++c) {
        const int col = c * 16 + rl;
        const float bL = biasL[col];
        const float bR = biasR[col];
        #pragma unroll
        for (int r = 0; r < 2; ++r) {
            #pragma unroll
            for (int q = 0; q < 4; ++q) {
                const int row = rows0 + 16 * r + g * 4 + q;
                if (row < m_rows) {
                    YL[(size_t)row * DH + col] = accL[r][c][q] + bL;
                    YR[(size_t)row * DH + col] = accR[r][c][q] + bR;
                }
            }
        }
    }
}

// ========== gemm1 + fused final LayerNorm: out = LN(A@W + b; g, bt) ==========
__global__ __launch_bounds__(256) void gemm1_ln_kernel(
    const float* __restrict__ A, int m_rows,
    const short* __restrict__ Whi, const short* __restrict__ Wlo,
    const float* __restrict__ bias,
    const float* __restrict__ gam, const float* __restrict__ bet,
    float* __restrict__ out)
{
    const int w    = threadIdx.x >> 6;
    const int lane = threadIdx.x & 63;
    const int rows0 = blockIdx.x * MTILE + w * 32;
    const int g  = lane >> 4;
    const int rl = lane & 15;

    f32x4 acc[2][8];
    #pragma unroll
    for (int r = 0; r < 2; ++r)
        #pragma unroll
        for (int c = 0; c < 8; ++c)
            acc[r][c] = (f32x4){0.f, 0.f, 0.f, 0.f};

    for (int t = 0; t < 4; ++t) {
        uint4v hw[2], lw[2];
        #pragma unroll
        for (int r = 0; r < 2; ++r) {
            int arow = rows0 + 16 * r + rl;
            arow = (arow < m_rows) ? arow : (m_rows - 1);
            const float* ap = A + (size_t)arow * DH + t * 32 + g * 8;
            const float4 f0 = *(const float4*)ap;
            const float4 f1 = *(const float4*)(ap + 4);
            unsigned h0, l0, h1, l1, h2, l2, h3, l3;
            split_pair(f0.x, f0.y, h0, l0);
            split_pair(f0.z, f0.w, h1, l1);
            split_pair(f1.x, f1.y, h2, l2);
            split_pair(f1.z, f1.w, h3, l3);
            hw[r] = (uint4v){h0, h1, h2, h3};
            lw[r] = (uint4v){l0, l1, l2, l3};
        }
        const short8 ahi0 = __builtin_bit_cast(short8, hw[0]);
        const short8 ahi1 = __builtin_bit_cast(short8, hw[1]);
        const short8 alo0 = __builtin_bit_cast(short8, lw[0]);
        const short8 alo1 = __builtin_bit_cast(short8, lw[1]);

        #pragma unroll
        for (int c = 0; c < 8; ++c) {
            const int fidx = ((t * 8 + c) * 64 + lane) * 8;
            const short8 bh = *(const short8*)(Whi + fidx);
            const short8 bl = *(const short8*)(Wlo + fidx);
            acc[0][c] = __builtin_amdgcn_mfma_f32_16x16x32_bf16(ahi0, bh, acc[0][c], 0, 0, 0);
            acc[1][c] = __builtin_amdgcn_mfma_f32_16x16x32_bf16(ahi1, bh, acc[1][c], 0, 0, 0);
            acc[0][c] = __builtin_amdgcn_mfma_f32_16x16x32_bf16(alo0, bh, acc[0][c], 0, 0, 0);
            acc[1][c] = __builtin_amdgcn_mfma_f32_16x16x32_bf16(alo1, bh, acc[1][c], 0, 0, 0);
            acc[0][c] = __builtin_amdgcn_mfma_f32_16x16x32_bf16(ahi0, bl, acc[0][c], 0, 0, 0);
            acc[1][c] = __builtin_amdgcn_mfma_f32_16x16x32_bf16(ahi1, bl, acc[1][c], 0, 0, 0);
        }
    }

    // ---- fused LayerNorm epilogue ----
    float bb[8], gg[8], bt8[8];
    #pragma unroll
    for (int c = 0; c < 8; ++c) {
        const int col = c * 16 + rl;
        bb[c] = bias[col];  gg[c] = gam[col];  bt8[c] = bet[col];
    }
    #pragma unroll
    for (int r = 0; r < 2; ++r) {
        #pragma unroll
        for (int q = 0; q < 4; ++q) {
            float v[8];
            float s = 0.f, sq = 0.f;
            #pragma unroll
            for (int c = 0; c < 8; ++c) {
                v[c] = acc[r][c][q] + bb[c];
                s  += v[c];
                sq  = fmaf(v[c], v[c], sq);
            }
            // reduce across the 16 rl-lanes of this g-group
            #pragma unroll
            for (int off = 1; off < 16; off <<= 1) {
                s  += __shfl_xor(s,  off);
                sq += __shfl_xor(sq, off);
            }
            const float mu   = s * (1.f / 128.f);
            const float var  = sq * (1.f / 128.f) - mu * mu;
            const float rstd = rsqrtf(var + LN_EPS);
            const int row = rows0 + 16 * r + g * 4 + q;
            if (row < m_rows) {
                #pragma unroll
                for (int c = 0; c < 8; ++c)
                    out[(size_t)row * DH + c * 16 + rl] =
                        (v[c] - mu) * rstd * gg[c] + bt8[c];
            }
        }
    }
}

// ========== per-node axl precompute: axl[n,h] = 0.6*log2e * sum_c att[h,c]*xl[n,c] ==========
__global__ __launch_bounds__(256) void axl_kernel(
    const float* __restrict__ xl, const float* __restrict__ att,
    float* __restrict__ axl)
{
    const int n  = blockIdx.x * 8 + (threadIdx.x >> 5);
    const int cl = threadIdx.x & 31;
    if (n >= N_NODES) return;
    const int c0 = cl * 4;
    const float4 xv = *(const float4*)(xl + (size_t)n * DH + c0);
    const float4 at = *(const float4*)(att + c0);
    float p = xv.x * at.x + xv.y * at.y + xv.z * at.z + xv.w * at.w;
    p += __shfl_xor(p, 1);
    p += __shfl_xor(p, 2);
    p += __shfl_xor(p, 4);
    if ((cl & 7) == 0)
        axl[n * NH + (cl >> 3)] = p * (0.6f * LOG2E);
}

// ========================= CSR construction =========================
__global__ __launch_bounds__(256) void degree_kernel(
    const int* __restrict__ eidx, int* __restrict__ deg)
{
    const int i = blockIdx.x * 256 + threadIdx.x;
    if (i >= ETOT) return;
    const int d = (i < N_EDGES) ? eidx[N_EDGES + i] : (i - N_EDGES);
    atomicAdd(&deg[d], 1);
}

__global__ __launch_bounds__(256) void block_sum_kernel(
    const int* __restrict__ deg, int* __restrict__ bsum)
{
    const int i    = blockIdx.x * 256 + threadIdx.x;
    const int lane = threadIdx.x & 63;
    const int wid  = threadIdx.x >> 6;
    int v = (i < N_NODES) ? deg[i] : 0;
    #pragma unroll
    for (int off = 32; off; off >>= 1) v += __shfl_xor(v, off);
    __shared__ int ws[4];
    if (lane == 0) ws[wid] = v;
    __syncthreads();
    if (threadIdx.x == 0) bsum[blockIdx.x] = ws[0] + ws[1] + ws[2] + ws[3];
}

__global__ __launch_bounds__(256) void scan_partials_kernel(
    const int* __restrict__ bsum, int* __restrict__ boff)
{
    const int t    = threadIdx.x;
    const int lane = t & 63;
    const int wid  = t >> 6;
    int v = (t < NBLK) ? bsum[t] : 0;
    int inc = v;
    #pragma unroll
    for (int off = 1; off < 64; off <<= 1) {
        int u = __shfl_up(inc, off);
        if (lane >= off) inc += u;
    }
    __shared__ int ws[4];
    if (lane == 63) ws[wid] = inc;
    __syncthreads();
    int add = 0;
    for (int w = 0; w < wid; ++w) add += ws[w];
    if (t < NBLK) boff[t] = add + inc - v;
}

__global__ __launch_bounds__(256) void rowptr_kernel(
    const int* __restrict__ deg, const int* __restrict__ boff,
    int* __restrict__ rowptr, int* __restrict__ cursor)
{
    const int i    = blockIdx.x * 256 + threadIdx.x;
    const int lane = threadIdx.x & 63;
    const int wid  = threadIdx.x >> 6;
    int v = (i < N_NODES) ? deg[i] : 0;
    int inc = v;
    #pragma unroll
    for (int off = 1; off < 64; off <<= 1) {
        int u = __shfl_up(inc, off);
        if (lane >= off) inc += u;
    }
    __shared__ int ws[4];
    if (lane == 63) ws[wid] = inc;
    __syncthreads();
    int add = boff[blockIdx.x];
    for (int w = 0; w < wid; ++w) add += ws[w];
    if (i < N_NODES) {
        const int ex = add + inc - v;
        rowptr[i] = ex;
        cursor[i] = ex;
    }
}

__global__ __launch_bounds__(256) void scatter_kernel(
    const int* __restrict__ eidx, int* __restrict__ cursor,
    int* __restrict__ csr_src)
{
    const int i = blockIdx.x * 256 + threadIdx.x;
    if (i >= ETOT) return;
    int s, d;
    if (i < N_EDGES) { s = eidx[i]; d = eidx[N_EDGES + i]; }
    else             { s = d = i - N_EDGES; }
    const int slot = atomicAdd(&cursor[d], 1);
    csr_src[slot] = s;
}

// ====== fused per-node GAT: |abs|-decomposed logits + exact defer-max softmax ======
// wave = one dst node; 32 lanes/edge, 4 ch/lane, 2 edge slots (halves), base-2 domain
__global__ __launch_bounds__(256) void gat_node_kernel(
    const int* __restrict__ rowptr, const int* __restrict__ deg,
    const int* __restrict__ csr_src,
    const float* __restrict__ xl, const float* __restrict__ xr,
    const float* __restrict__ axl,
    const float* __restrict__ att, const float* __restrict__ bias,
    const float* __restrict__ gam, const float* __restrict__ bet,
    float* __restrict__ out)
{
    const int n    = blockIdx.x * 4 + (threadIdx.x >> 6);
    const int lane = threadIdx.x & 63;
    if (n >= N_NODES) return;
    const int half = lane >> 5;
    const int cl   = lane & 31;
    const int c0   = cl * 4;
    const int h    = cl >> 3;          // head of this lane's 4 channels

    const float4 xrv = *(const float4*)(xr + (size_t)n * DH + c0);
    float4 atv = *(const float4*)(att + c0);
    const float S4 = 0.4f * LOG2E;
    atv.x *= S4; atv.y *= S4; atv.z *= S4; atv.w *= S4;

    float m0 = -INFINITY, d0 = 0.f;
    float4 p0 = {0.f, 0.f, 0.f, 0.f};
    float m1 = -INFINITY, d1 = 0.f;
    float4 p1 = {0.f, 0.f, 0.f, 0.f};

    const int beg = rowptr[n];
    const int end = beg + deg[n];
    int e = beg;

    for (; e + 4 <= end; e += 4) {
        const int eb = e + 2 * half;
        const int s0 = csr_src[eb];
        const int s1 = csr_src[eb + 1];
        const float4 x0 = *(const float4*)(xl + (size_t)s0 * DH + c0);
        const float4 x1 = *(const float4*)(xl + (size_t)s1 * DH + c0);
        const float a0 = axl[s0 * NH + h];
        const float a1 = axl[s1 * NH + h];

        float t, l0 = 0.f, l1 = 0.f;
        t = x0.x + xrv.x; l0 = fmaf(atv.x, fabsf(t), l0);
        t = x0.y + xrv.y; l0 = fmaf(atv.y, fabsf(t), l0);
        t = x0.z + xrv.z; l0 = fmaf(atv.z, fabsf(t), l0);
        t = x0.w + xrv.w; l0 = fmaf(atv.w, fabsf(t), l0);
        t = x1.x + xrv.x; l1 = fmaf(atv.x, fabsf(t), l1);
        t = x1.y + xrv.y; l1 = fmaf(atv.y, fabsf(t), l1);
        t = x1.z + xrv.z; l1 = fmaf(atv.z, fabsf(t), l1);
        t = x1.w + xrv.w; l1 = fmaf(atv.w, fabsf(t), l1);

        l0 += __shfl_xor(l0, 1);  l1 += __shfl_xor(l1, 1);
        l0 += __shfl_xor(l0, 2);  l1 += __shfl_xor(l1, 2);
        l0 += __shfl_xor(l0, 4);  l1 += __shfl_xor(l1, 4);
        l0 += a0;  l1 += a1;

        if (__any((l0 > m0) | (l1 > m1))) {
            // rescale path (rare after max stabilizes)
            float nm, sc, w;
            nm = fmaxf(m0, l0); sc = exp2f(m0 - nm); w = exp2f(l0 - nm);
            d0 = fmaf(d0, sc, w);
            p0.x = fmaf(p0.x, sc, x0.x * w);  p0.y = fmaf(p0.y, sc, x0.y * w);
            p0.z = fmaf(p0.z, sc, x0.z * w);  p0.w = fmaf(p0.w, sc, x0.w * w);
            m0 = nm;
            nm = fmaxf(m1, l1); sc = exp2f(m1 - nm); w = exp2f(l1 - nm);
            d1 = fmaf(d1, sc, w);
            p1.x = fmaf(p1.x, sc, x1.x * w);  p1.y = fmaf(p1.y, sc, x1.y * w);
            p1.z = fmaf(p1.z, sc, x1.z * w);  p1.w = fmaf(p1.w, sc, x1.w * w);
            m1 = nm;
        } else {
            // fast path: max unchanged, exact
            const float w0 = exp2f(l0 - m0);
            const float w1 = exp2f(l1 - m1);
            d0 += w0;  d1 += w1;
            p0.x = fmaf(x0.x, w0, p0.x);  p0.y = fmaf(x0.y, w0, p0.y);
            p0.z = fmaf(x0.z, w0, p0.z);  p0.w = fmaf(x0.w, w0, p0.w);
            p1.x = fmaf(x1.x, w1, p1.x);  p1.y = fmaf(x1.y, w1, p1.y);
            p1.z = fmaf(x1.z, w1, p1.z);  p1.w = fmaf(x1.w, w1, p1.w);
        }
    }

    // tail: up to 3 edges, 2 per iter with masking -> state 0
    for (; e < end; e += 2) {
        const int ei     = e + half;
        const bool valid = (ei < end);
        const int s = csr_src[valid ? ei : beg];
        const float4 xv = *(const float4*)(xl + (size_t)s * DH + c0);
        const float a = axl[s * NH + h];

        float t, l = 0.f;
        t = xv.x + xrv.x; l = fmaf(atv.x, fabsf(t), l);
        t = xv.y + xrv.y; l = fmaf(atv.y, fabsf(t), l);
        t = xv.z + xrv.z; l = fmaf(atv.z, fabsf(t), l);
        t = xv.w + xrv.w; l = fmaf(atv.w, fabsf(t), l);
        l += __shfl_xor(l, 1);
        l += __shfl_xor(l, 2);
        l += __shfl_xor(l, 4);
        l += a;

        float nm = fmaxf(m0, l);
        float sc = exp2f(m0 - nm);
        float w  = exp2f(l - nm);
        if (!valid) { nm = m0; sc = 1.f; w = 0.f; }
        d0 = fmaf(d0, sc, w);
        p0.x = fmaf(p0.x, sc, xv.x * w);  p0.y = fmaf(p0.y, sc, xv.y * w);
        p0.z = fmaf(p0.z, sc, xv.z * w);  p0.w = fmaf(p0.w, sc, xv.w * w);
        m0 = nm;
    }

    // merge state1 into state0 (guarded: either m may be -inf)
    {
        const float M  = fmaxf(m0, m1);
        const float ea = (m0 == M) ? 1.f : exp2f(m0 - M);
        const float eb = (m1 == M) ? 1.f : exp2f(m1 - M);
        d0  = d0 * ea + d1 * eb;
        p0.x = p0.x * ea + p1.x * eb;  p0.y = p0.y * ea + p1.y * eb;
        p0.z = p0.z * ea + p1.z * eb;  p0.w = p0.w * ea + p1.w * eb;
        m0 = M;
    }
    // cross-half merge (lane ^ 32)
    {
        const float mo = __shfl_xor(m0, 32);
        const float dd = __shfl_xor(d0, 32);
        const float qx = __shfl_xor(p0.x, 32), qy = __shfl_xor(p0.y, 32);
        const float qz = __shfl_xor(p0.z, 32), qw = __shfl_xor(p0.w, 32);
        const float M  = fmaxf(m0, mo);
        const float ea = (m0 == M) ? 1.f : exp2f(m0 - M);
        const float eb = (mo == M) ? 1.f : exp2f(mo - M);
        d0  = d0 * ea + dd * eb;
        p0.x = p0.x * ea + qx * eb;  p0.y = p0.y * ea + qy * eb;
        p0.z = p0.z * ea + qz * eb;  p0.w = p0.w * ea + qw * eb;
    }

    const float inv = 1.f / d0;
    const float4 bi = *(const float4*)(bias + c0);
    float v0 = p0.x * inv + bi.x;
    float v1 = p0.y * inv + bi.y;
    float v2 = p0.z * inv + bi.z;
    float v3 = p0.w * inv + bi.w;

    // LayerNorm over 128 ch = 32 lanes x 4 (xor 1..16 stays within half)
    float s2 = v0 + v1 + v2 + v3;
    float sq = v0*v0 + v1*v1 + v2*v2 + v3*v3;
    #pragma unroll
    for (int off = 16; off; off >>= 1) {
        s2 += __shfl_xor(s2, off);
        sq += __shfl_xor(sq, off);
    }
    const float mu   = s2 * (1.f / 128.f);
    const float var  = sq * (1.f / 128.f) - mu * mu;
    const float rstd = rsqrtf(var + LN_EPS);

    const float4 gm = *(const float4*)(gam + c0);
    const float4 bt = *(const float4*)(bet + c0);
    float y0 = gelu_exact((v0 - mu) * rstd * gm.x + bt.x);
    float y1 = gelu_exact((v1 - mu) * rstd * gm.y + bt.y);
    float y2 = gelu_exact((v2 - mu) * rstd * gm.z + bt.z);
    float y3 = gelu_exact((v3 - mu) * rstd * gm.w + bt.w);

    if (half == 0) {
        float4 yv = {y0, y1, y2, y3};
        *(float4*)(out + (size_t)n * DH + c0) = yv;
    }
}

extern "C" void kernel_launch(void* const* d_in, const int* in_sizes, int n_in,
                              void* d_out, int out_size, void* d_ws, size_t ws_size,
                              hipStream_t stream)
{
    const float* x    = (const float*)d_in[0];
    const int*   eidx = (const int*)  d_in[1];

    const float* Wl[2]   = { (const float*)d_in[2],  (const float*)d_in[10] };
    const float* bl[2]   = { (const float*)d_in[3],  (const float*)d_in[11] };
    const float* Wr[2]   = { (const float*)d_in[4],  (const float*)d_in[12] };
    const float* br[2]   = { (const float*)d_in[5],  (const float*)d_in[13] };
    const float* att[2]  = { (const float*)d_in[6],  (const float*)d_in[14] };
    const float* bias[2] = { (const float*)d_in[7],  (const float*)d_in[15] };
    const float* gam[2]  = { (const float*)d_in[8],  (const float*)d_in[16] };
    const float* bet[2]  = { (const float*)d_in[9],  (const float*)d_in[17] };
    const float* Wout    = (const float*)d_in[18];
    const float* bout    = (const float*)d_in[19];
    const float* gout    = (const float*)d_in[20];
    const float* boutln  = (const float*)d_in[21];

    float* out = (float*)d_out;

    const size_t NF = (size_t)N_NODES * DH;
    float* xl      = (float*)d_ws;
    float* xr      = xl + NF;
    float* h1      = xr + NF;
    float* h2      = h1 + NF;
    int*   csr_src = (int*)(h2 + NF);
    int*   deg     = csr_src + ETOT;
    int*   rowptr  = deg + N_NODES;
    int*   cursor  = rowptr + N_NODES;
    int*   bsum    = cursor + N_NODES;
    int*   boff    = bsum + NBLK;
    short* whi     = (short*)(boff + NBLK);   // 5 * 16384 shorts
    short* wlo     = whi + 5 * 16384;
    float* axlbuf  = (float*)(wlo + 5 * 16384);   // N_NODES * 4

    const int etBlocks   = (ETOT + 255) / 256;
    const int nodeBlocks = N_NODES / 4;
    const int gemmBlocks = (N_NODES + MTILE - 1) / MTILE;   // 391
    const int axlBlocks  = (N_NODES + 7) / 8;

    #define WP(i) (whi + (i) * 16384), (wlo + (i) * 16384)

    // ---- CSR (deterministic rebuild every call) ----
    hipMemsetAsync(deg, 0, N_NODES * sizeof(int), stream);
    degree_kernel       <<<etBlocks, 256, 0, stream>>>(eidx, deg);
    block_sum_kernel    <<<NBLK, 256, 0, stream>>>(deg, bsum);
    scan_partials_kernel<<<1, 256, 0, stream>>>(bsum, boff);
    rowptr_kernel       <<<NBLK, 256, 0, stream>>>(deg, boff, rowptr, cursor);
    scatter_kernel      <<<etBlocks, 256, 0, stream>>>(eidx, cursor, csr_src);

    // ---- pack all 5 weight matrices ----
    pack_w_kernel<<<320, 256, 0, stream>>>(Wl[0], Wr[0], Wl[1], Wr[1], Wout, whi, wlo);

    // ---- layer 0 ----
    gemm2_mfma_kernel<<<gemmBlocks, 256, 0, stream>>>(
        x, N_NODES, WP(0), bl[0], xl, WP(1), br[0], xr);
    axl_kernel<<<axlBlocks, 256, 0, stream>>>(xl, att[0], axlbuf);
    gat_node_kernel<<<nodeBlocks, 256, 0, stream>>>(rowptr, deg, csr_src, xl, xr, axlbuf,
                                                    att[0], bias[0], gam[0], bet[0], h1);
    // ---- layer 1 ----
    gemm2_mfma_kernel<<<gemmBlocks, 256, 0, stream>>>(
        h1, N_NODES, WP(2), bl[1], xl, WP(3), br[1], xr);
    axl_kernel<<<axlBlocks, 256, 0, stream>>>(xl, att[1], axlbuf);
    gat_node_kernel<<<nodeBlocks, 256, 0, stream>>>(rowptr, deg, csr_src, xl, xr, axlbuf,
                                                    att[1], bias[1], gam[1], bet[1], h2);

    // ---- output projection + fused final LayerNorm ----
    gemm1_ln_kernel<<<gemmBlocks, 256, 0, stream>>>(
        h2, N_NODES, WP(4), bout, gout, boutln, out);
}

// Round 7
// 338.739 us; speedup vs baseline: 1.1537x; 1.1537x over previous
//
#include <hip/hip_runtime.h>
#include <math.h>

#define N_NODES 50000
#define N_EDGES 800000
#define ETOT    (N_EDGES + N_NODES)
#define DH      128
#define NH      4
#define LN_EPS  1e-5f
#define NBLK    ((N_NODES + 255) / 256)   // 196 scan blocks
#define LOG2E   1.4426950408889634f

typedef __attribute__((ext_vector_type(8))) short short8;
typedef __attribute__((ext_vector_type(4))) float f32x4;

// ---------- fp32 -> bf16 (RNE) split helpers ----------
__device__ __forceinline__ unsigned short f2bf(float f) {
    unsigned u = __float_as_uint(f);
    u += 0x7FFFu + ((u >> 16) & 1u);
    return (unsigned short)(u >> 16);
}
__device__ __forceinline__ float bf2f(unsigned short h) {
    return __uint_as_float(((unsigned)h) << 16);
}

// ---------- fast exact-GELU (A&S 7.1.26 erf, max err ~1.5e-7) ----------
__device__ __forceinline__ float gelu_exact(float x) {
    const float z  = x * 0.70710678118654752f;
    const float az = fabsf(z);
    const float tt = __builtin_amdgcn_rcpf(fmaf(0.3275911f, az, 1.f));
    float p = fmaf(1.061405429f, tt, -1.453152027f);
    p = fmaf(p, tt, 1.421413741f);
    p = fmaf(p, tt, -0.284496736f);
    p = fmaf(p, tt, 0.254829592f);
    p = p * tt;
    const float ez = exp2f(-(z * z) * LOG2E);
    float er = fmaf(-p, ez, 1.f);
    er = copysignf(er, z);
    return x * fmaf(0.5f, er, 0.5f);
}

// ========== pack 5 weight matrices into MFMA B-fragment order (hi/lo) ==========
__global__ __launch_bounds__(256) void pack_w_kernel(
    const float* __restrict__ W0, const float* __restrict__ W1,
    const float* __restrict__ W2, const float* __restrict__ W3,
    const float* __restrict__ W4,
    short* __restrict__ hi, short* __restrict__ lo)
{
    const int idx = blockIdx.x * 256 + threadIdx.x;   // 0..81919
    const int mat = idx >> 14;
    const int rem = idx & 16383;
    const int t = rem >> 12, c = (rem >> 9) & 7, l = (rem >> 3) & 63, j = rem & 7;
    const int k = t * 32 + (l >> 4) * 8 + j;
    const int n = c * 16 + (l & 15);
    const float* W = (mat == 0) ? W0 : (mat == 1) ? W1 : (mat == 2) ? W2
                   : (mat == 3) ? W3 : W4;
    const float v = W[k * DH + n];
    const unsigned short h = f2bf(v);
    hi[idx] = (short)h;
    lo[idx] = (short)f2bf(v - bf2f(h));
}

// ========== split-bf16 MFMA GEMM: Y = A @ W + b (R4 known-good form) ==========
#define MTILE 128
__global__ __launch_bounds__(256) void gemm_mfma_kernel(
    const float* __restrict__ A, int m_rows,
    const short* __restrict__ Whi0, const short* __restrict__ Wlo0,
    const float* __restrict__ bias0, float* __restrict__ Y0,
    const short* __restrict__ Whi1, const short* __restrict__ Wlo1,
    const float* __restrict__ bias1, float* __restrict__ Y1)
{
    const int w    = threadIdx.x >> 6;
    const int lane = threadIdx.x & 63;
    const short* Whi  = blockIdx.y ? Whi1  : Whi0;
    const short* Wlo  = blockIdx.y ? Wlo1  : Wlo0;
    const float* bias = blockIdx.y ? bias1 : bias0;
    float*       Y    = blockIdx.y ? Y1    : Y0;

    const int rows0 = blockIdx.x * MTILE + w * 32;
    const int g  = lane >> 4;
    const int rl = lane & 15;

    f32x4 acc[2][8];
    #pragma unroll
    for (int r = 0; r < 2; ++r)
        #pragma unroll
        for (int c = 0; c < 8; ++c)
            acc[r][c] = (f32x4){0.f, 0.f, 0.f, 0.f};

    for (int t = 0; t < 4; ++t) {
        short8 ahi[2], alo[2];
        #pragma unroll
        for (int r = 0; r < 2; ++r) {
            int arow = rows0 + 16 * r + rl;
            arow = (arow < m_rows) ? arow : (m_rows - 1);
            const float* ap = A + (size_t)arow * DH + t * 32 + g * 8;
            const float4 f0 = *(const float4*)ap;
            const float4 f1 = *(const float4*)(ap + 4);
            const float fv[8] = {f0.x, f0.y, f0.z, f0.w, f1.x, f1.y, f1.z, f1.w};
            #pragma unroll
            for (int j = 0; j < 8; ++j) {
                const unsigned short h = f2bf(fv[j]);
                ahi[r][j] = (short)h;
                alo[r][j] = (short)f2bf(fv[j] - bf2f(h));
            }
        }
        #pragma unroll
        for (int c = 0; c < 8; ++c) {
            const int fidx = ((t * 8 + c) * 64 + lane) * 8;
            const short8 bhi = *(const short8*)(Whi + fidx);
            const short8 blo = *(const short8*)(Wlo + fidx);
            acc[0][c] = __builtin_amdgcn_mfma_f32_16x16x32_bf16(ahi[0], bhi, acc[0][c], 0, 0, 0);
            acc[1][c] = __builtin_amdgcn_mfma_f32_16x16x32_bf16(ahi[1], bhi, acc[1][c], 0, 0, 0);
            acc[0][c] = __builtin_amdgcn_mfma_f32_16x16x32_bf16(alo[0], bhi, acc[0][c], 0, 0, 0);
            acc[1][c] = __builtin_amdgcn_mfma_f32_16x16x32_bf16(alo[1], bhi, acc[1][c], 0, 0, 0);
            acc[0][c] = __builtin_amdgcn_mfma_f32_16x16x32_bf16(ahi[0], blo, acc[0][c], 0, 0, 0);
            acc[1][c] = __builtin_amdgcn_mfma_f32_16x16x32_bf16(ahi[1], blo, acc[1][c], 0, 0, 0);
        }
    }
    #pragma unroll
    for (int c = 0; c < 8; ++c) {
        const int col = c * 16 + rl;
        const float bb = bias[col];
        #pragma unroll
        for (int r = 0; r < 2; ++r) {
            #pragma unroll
            for (int q = 0; q < 4; ++q) {
                const int row = rows0 + 16 * r + g * 4 + q;
                if (row < m_rows) Y[(size_t)row * DH + col] = acc[r][c][q] + bb;
            }
        }
    }
}

// ========== gemm1 + fused final LayerNorm: out = LN(A@W + b; g, bt) ==========
__global__ __launch_bounds__(256) void gemm1_ln_kernel(
    const float* __restrict__ A, int m_rows,
    const short* __restrict__ Whi, const short* __restrict__ Wlo,
    const float* __restrict__ bias,
    const float* __restrict__ gam, const float* __restrict__ bet,
    float* __restrict__ out)
{
    const int w    = threadIdx.x >> 6;
    const int lane = threadIdx.x & 63;
    const int rows0 = blockIdx.x * MTILE + w * 32;
    const int g  = lane >> 4;
    const int rl = lane & 15;

    f32x4 acc[2][8];
    #pragma unroll
    for (int r = 0; r < 2; ++r)
        #pragma unroll
        for (int c = 0; c < 8; ++c)
            acc[r][c] = (f32x4){0.f, 0.f, 0.f, 0.f};

    for (int t = 0; t < 4; ++t) {
        short8 ahi[2], alo[2];
        #pragma unroll
        for (int r = 0; r < 2; ++r) {
            int arow = rows0 + 16 * r + rl;
            arow = (arow < m_rows) ? arow : (m_rows - 1);
            const float* ap = A + (size_t)arow * DH + t * 32 + g * 8;
            const float4 f0 = *(const float4*)ap;
            const float4 f1 = *(const float4*)(ap + 4);
            const float fv[8] = {f0.x, f0.y, f0.z, f0.w, f1.x, f1.y, f1.z, f1.w};
            #pragma unroll
            for (int j = 0; j < 8; ++j) {
                const unsigned short h = f2bf(fv[j]);
                ahi[r][j] = (short)h;
                alo[r][j] = (short)f2bf(fv[j] - bf2f(h));
            }
        }
        #pragma unroll
        for (int c = 0; c < 8; ++c) {
            const int fidx = ((t * 8 + c) * 64 + lane) * 8;
            const short8 bh = *(const short8*)(Whi + fidx);
            const short8 bl = *(const short8*)(Wlo + fidx);
            acc[0][c] = __builtin_amdgcn_mfma_f32_16x16x32_bf16(ahi[0], bh, acc[0][c], 0, 0, 0);
            acc[1][c] = __builtin_amdgcn_mfma_f32_16x16x32_bf16(ahi[1], bh, acc[1][c], 0, 0, 0);
            acc[0][c] = __builtin_amdgcn_mfma_f32_16x16x32_bf16(alo[0], bh, acc[0][c], 0, 0, 0);
            acc[1][c] = __builtin_amdgcn_mfma_f32_16x16x32_bf16(alo[1], bh, acc[1][c], 0, 0, 0);
            acc[0][c] = __builtin_amdgcn_mfma_f32_16x16x32_bf16(ahi[0], bl, acc[0][c], 0, 0, 0);
            acc[1][c] = __builtin_amdgcn_mfma_f32_16x16x32_bf16(ahi[1], bl, acc[1][c], 0, 0, 0);
        }
    }

    float bb[8], gg[8], bt8[8];
    #pragma unroll
    for (int c = 0; c < 8; ++c) {
        const int col = c * 16 + rl;
        bb[c] = bias[col];  gg[c] = gam[col];  bt8[c] = bet[col];
    }
    #pragma unroll
    for (int r = 0; r < 2; ++r) {
        #pragma unroll
        for (int q = 0; q < 4; ++q) {
            float v[8];
            float s = 0.f, sq = 0.f;
            #pragma unroll
            for (int c = 0; c < 8; ++c) {
                v[c] = acc[r][c][q] + bb[c];
                s  += v[c];
                sq  = fmaf(v[c], v[c], sq);
            }
            #pragma unroll
            for (int off = 1; off < 16; off <<= 1) {
                s  += __shfl_xor(s,  off);
                sq += __shfl_xor(sq, off);
            }
            const float mu   = s * (1.f / 128.f);
            const float var  = sq * (1.f / 128.f) - mu * mu;
            const float rstd = rsqrtf(var + LN_EPS);
            const int row = rows0 + 16 * r + g * 4 + q;
            if (row < m_rows) {
                #pragma unroll
                for (int c = 0; c < 8; ++c)
                    out[(size_t)row * DH + c * 16 + rl] =
                        (v[c] - mu) * rstd * gg[c] + bt8[c];
            }
        }
    }
}

// ========================= CSR construction =========================
__global__ __launch_bounds__(256) void degree_kernel(
    const int* __restrict__ eidx, int* __restrict__ deg)
{
    const int i = blockIdx.x * 256 + threadIdx.x;
    if (i >= ETOT) return;
    const int d = (i < N_EDGES) ? eidx[N_EDGES + i] : (i - N_EDGES);
    atomicAdd(&deg[d], 1);
}

__global__ __launch_bounds__(256) void block_sum_kernel(
    const int* __restrict__ deg, int* __restrict__ bsum)
{
    const int i    = blockIdx.x * 256 + threadIdx.x;
    const int lane = threadIdx.x & 63;
    const int wid  = threadIdx.x >> 6;
    int v = (i < N_NODES) ? deg[i] : 0;
    #pragma unroll
    for (int off = 32; off; off >>= 1) v += __shfl_xor(v, off);
    __shared__ int ws[4];
    if (lane == 0) ws[wid] = v;
    __syncthreads();
    if (threadIdx.x == 0) bsum[blockIdx.x] = ws[0] + ws[1] + ws[2] + ws[3];
}

__global__ __launch_bounds__(256) void scan_partials_kernel(
    const int* __restrict__ bsum, int* __restrict__ boff)
{
    const int t    = threadIdx.x;
    const int lane = t & 63;
    const int wid  = t >> 6;
    int v = (t < NBLK) ? bsum[t] : 0;
    int inc = v;
    #pragma unroll
    for (int off = 1; off < 64; off <<= 1) {
        int u = __shfl_up(inc, off);
        if (lane >= off) inc += u;
    }
    __shared__ int ws[4];
    if (lane == 63) ws[wid] = inc;
    __syncthreads();
    int add = 0;
    for (int w = 0; w < wid; ++w) add += ws[w];
    if (t < NBLK) boff[t] = add + inc - v;
}

__global__ __launch_bounds__(256) void rowptr_kernel(
    const int* __restrict__ deg, const int* __restrict__ boff,
    int* __restrict__ rowptr, int* __restrict__ cursor)
{
    const int i    = blockIdx.x * 256 + threadIdx.x;
    const int lane = threadIdx.x & 63;
    const int wid  = threadIdx.x >> 6;
    int v = (i < N_NODES) ? deg[i] : 0;
    int inc = v;
    #pragma unroll
    for (int off = 1; off < 64; off <<= 1) {
        int u = __shfl_up(inc, off);
        if (lane >= off) inc += u;
    }
    __shared__ int ws[4];
    if (lane == 63) ws[wid] = inc;
    __syncthreads();
    int add = boff[blockIdx.x];
    for (int w = 0; w < wid; ++w) add += ws[w];
    if (i < N_NODES) {
        const int ex = add + inc - v;
        rowptr[i] = ex;
        cursor[i] = ex;
    }
}

__global__ __launch_bounds__(256) void scatter_kernel(
    const int* __restrict__ eidx, int* __restrict__ cursor,
    int* __restrict__ csr_src)
{
    const int i = blockIdx.x * 256 + threadIdx.x;
    if (i >= ETOT) return;
    int s, d;
    if (i < N_EDGES) { s = eidx[i]; d = eidx[N_EDGES + i]; }
    else             { s = d = i - N_EDGES; }
    const int slot = atomicAdd(&cursor[d], 1);
    csr_src[slot] = s;
}

// ====== fused per-node GAT: no-max base-2 softmax, branch-free masked loop ======
// wave = one dst node; 32 lanes/edge, 4 ch/lane, 2 edge slots (halves)
__global__ __launch_bounds__(256) void gat_node_kernel(
    const int* __restrict__ rowptr, const int* __restrict__ deg,
    const int* __restrict__ csr_src,
    const float* __restrict__ xl, const float* __restrict__ xr,
    const float* __restrict__ att, const float* __restrict__ bias,
    const float* __restrict__ gam, const float* __restrict__ bet,
    float* __restrict__ out)
{
    const int n    = blockIdx.x * 4 + (threadIdx.x >> 6);
    const int lane = threadIdx.x & 63;
    if (n >= N_NODES) return;
    const int half = lane >> 5;
    const int cl   = lane & 31;
    const int c0   = cl * 4;

    const float4 xrv = *(const float4*)(xr + (size_t)n * DH + c0);
    const float4 at  = *(const float4*)(att + c0);
    // leaky_relu(t) = 0.6t + 0.4|t|; fold log2(e) for base-2 exp
    float4 a6, a4;
    a6.x = at.x * (0.6f * LOG2E); a6.y = at.y * (0.6f * LOG2E);
    a6.z = at.z * (0.6f * LOG2E); a6.w = at.w * (0.6f * LOG2E);
    a4.x = at.x * (0.4f * LOG2E); a4.y = at.y * (0.4f * LOG2E);
    a4.z = at.z * (0.4f * LOG2E); a4.w = at.w * (0.4f * LOG2E);

    float dsum = 0.f;
    float4 p = {0.f, 0.f, 0.f, 0.f};

    const int beg = rowptr[n];
    const int end = beg + deg[n];

    for (int e = beg; e < end; e += 4) {
        const int eb = e + 2 * half;
        const bool v0 = (eb     < end);
        const bool v1 = (eb + 1 < end);
        const int s0 = v0 ? csr_src[eb]     : 0;
        const int s1 = v1 ? csr_src[eb + 1] : 0;
        const float4 x0 = *(const float4*)(xl + (unsigned)s0 * DH + c0);
        const float4 x1 = *(const float4*)(xl + (unsigned)s1 * DH + c0);

        float t, l0 = 0.f, l1 = 0.f;
        t = x0.x + xrv.x; l0 = fmaf(a6.x, t, fmaf(a4.x, fabsf(t), l0));
        t = x0.y + xrv.y; l0 = fmaf(a6.y, t, fmaf(a4.y, fabsf(t), l0));
        t = x0.z + xrv.z; l0 = fmaf(a6.z, t, fmaf(a4.z, fabsf(t), l0));
        t = x0.w + xrv.w; l0 = fmaf(a6.w, t, fmaf(a4.w, fabsf(t), l0));
        t = x1.x + xrv.x; l1 = fmaf(a6.x, t, fmaf(a4.x, fabsf(t), l1));
        t = x1.y + xrv.y; l1 = fmaf(a6.y, t, fmaf(a4.y, fabsf(t), l1));
        t = x1.z + xrv.z; l1 = fmaf(a6.z, t, fmaf(a4.z, fabsf(t), l1));
        t = x1.w + xrv.w; l1 = fmaf(a6.w, t, fmaf(a4.w, fabsf(t), l1));

        // head reduce: 8 lanes per head
        l0 += __shfl_xor(l0, 1);  l1 += __shfl_xor(l1, 1);
        l0 += __shfl_xor(l0, 2);  l1 += __shfl_xor(l1, 2);
        l0 += __shfl_xor(l0, 4);  l1 += __shfl_xor(l1, 4);

        // masked edges contribute exp2(-inf) = 0
        l0 = v0 ? l0 : -INFINITY;
        l1 = v1 ? l1 : -INFINITY;
        const float w0 = exp2f(l0);
        const float w1 = exp2f(l1);
        dsum += w0 + w1;
        p.x = fmaf(x0.x, w0, p.x);  p.x = fmaf(x1.x, w1, p.x);
        p.y = fmaf(x0.y, w0, p.y);  p.y = fmaf(x1.y, w1, p.y);
        p.z = fmaf(x0.z, w0, p.z);  p.z = fmaf(x1.z, w1, p.z);
        p.w = fmaf(x0.w, w0, p.w);  p.w = fmaf(x1.w, w1, p.w);
    }

    // cross-half merge (lane ^ 32): plain sums
    dsum += __shfl_xor(dsum, 32);
    p.x  += __shfl_xor(p.x, 32);
    p.y  += __shfl_xor(p.y, 32);
    p.z  += __shfl_xor(p.z, 32);
    p.w  += __shfl_xor(p.w, 32);

    const float inv = 1.f / dsum;
    const float4 bi = *(const float4*)(bias + c0);
    float v0 = p.x * inv + bi.x;
    float v1 = p.y * inv + bi.y;
    float v2 = p.z * inv + bi.z;
    float v3 = p.w * inv + bi.w;

    // LayerNorm over 128 ch = 32 lanes x 4 (xor 1..16 stays within half)
    float s2 = v0 + v1 + v2 + v3;
    float sq = v0*v0 + v1*v1 + v2*v2 + v3*v3;
    #pragma unroll
    for (int off = 16; off; off >>= 1) {
        s2 += __shfl_xor(s2, off);
        sq += __shfl_xor(sq, off);
    }
    const float mu   = s2 * (1.f / 128.f);
    const float var  = sq * (1.f / 128.f) - mu * mu;
    const float rstd = rsqrtf(var + LN_EPS);

    const float4 gm = *(const float4*)(gam + c0);
    const float4 bt = *(const float4*)(bet + c0);
    float y0 = gelu_exact((v0 - mu) * rstd * gm.x + bt.x);
    float y1 = gelu_exact((v1 - mu) * rstd * gm.y + bt.y);
    float y2 = gelu_exact((v2 - mu) * rstd * gm.z + bt.z);
    float y3 = gelu_exact((v3 - mu) * rstd * gm.w + bt.w);

    if (half == 0) {
        float4 yv = {y0, y1, y2, y3};
        *(float4*)(out + (size_t)n * DH + c0) = yv;
    }
}

extern "C" void kernel_launch(void* const* d_in, const int* in_sizes, int n_in,
                              void* d_out, int out_size, void* d_ws, size_t ws_size,
                              hipStream_t stream)
{
    const float* x    = (const float*)d_in[0];
    const int*   eidx = (const int*)  d_in[1];

    const float* Wl[2]   = { (const float*)d_in[2],  (const float*)d_in[10] };
    const float* bl[2]   = { (const float*)d_in[3],  (const float*)d_in[11] };
    const float* Wr[2]   = { (const float*)d_in[4],  (const float*)d_in[12] };
    const float* br[2]   = { (const float*)d_in[5],  (const float*)d_in[13] };
    const float* att[2]  = { (const float*)d_in[6],  (const float*)d_in[14] };
    const float* bias[2] = { (const float*)d_in[7],  (const float*)d_in[15] };
    const float* gam[2]  = { (const float*)d_in[8],  (const float*)d_in[16] };
    const float* bet[2]  = { (const float*)d_in[9],  (const float*)d_in[17] };
    const float* Wout    = (const float*)d_in[18];
    const float* bout    = (const float*)d_in[19];
    const float* gout    = (const float*)d_in[20];
    const float* boutln  = (const float*)d_in[21];

    float* out = (float*)d_out;

    const size_t NF = (size_t)N_NODES * DH;
    float* xl      = (float*)d_ws;
    float* xr      = xl + NF;
    float* h1      = xr + NF;
    float* h2      = h1 + NF;
    int*   csr_src = (int*)(h2 + NF);
    int*   deg     = csr_src + ETOT + 8;   // +8 pad
    int*   rowptr  = deg + N_NODES;
    int*   cursor  = rowptr + N_NODES;
    int*   bsum    = cursor + N_NODES;
    int*   boff    = bsum + NBLK;
    short* whi     = (short*)(boff + NBLK);   // 5 * 16384 shorts
    short* wlo     = whi + 5 * 16384;

    const int etBlocks   = (ETOT + 255) / 256;
    const int nodeBlocks = N_NODES / 4;
    const int gemmBlocks = (N_NODES + MTILE - 1) / MTILE;   // 391

    #define WP(i) (whi + (i) * 16384), (wlo + (i) * 16384)

    // ---- CSR (deterministic rebuild every call) ----
    hipMemsetAsync(deg, 0, N_NODES * sizeof(int), stream);
    degree_kernel       <<<etBlocks, 256, 0, stream>>>(eidx, deg);
    block_sum_kernel    <<<NBLK, 256, 0, stream>>>(deg, bsum);
    scan_partials_kernel<<<1, 256, 0, stream>>>(bsum, boff);
    rowptr_kernel       <<<NBLK, 256, 0, stream>>>(deg, boff, rowptr, cursor);
    scatter_kernel      <<<etBlocks, 256, 0, stream>>>(eidx, cursor, csr_src);

    // ---- pack all 5 weight matrices ----
    pack_w_kernel<<<320, 256, 0, stream>>>(Wl[0], Wr[0], Wl[1], Wr[1], Wout, whi, wlo);

    // ---- layer 0 ----
    gemm_mfma_kernel<<<dim3(gemmBlocks, 2), 256, 0, stream>>>(
        x, N_NODES, WP(0), bl[0], xl, WP(1), br[0], xr);
    gat_node_kernel<<<nodeBlocks, 256, 0, stream>>>(rowptr, deg, csr_src, xl, xr,
                                                    att[0], bias[0], gam[0], bet[0], h1);
    // ---- layer 1 ----
    gemm_mfma_kernel<<<dim3(gemmBlocks, 2), 256, 0, stream>>>(
        h1, N_NODES, WP(2), bl[1], xl, WP(3), br[1], xr);
    gat_node_kernel<<<nodeBlocks, 256, 0, stream>>>(rowptr, deg, csr_src, xl, xr,
                                                    att[1], bias[1], gam[1], bet[1], h2);

    // ---- output projection + fused final LayerNorm ----
    gemm1_ln_kernel<<<gemmBlocks, 256, 0, stream>>>(
        h2, N_NODES, WP(4), bout, gout, boutln, out);
}

// Round 8
// 324.436 us; speedup vs baseline: 1.2045x; 1.0441x over previous
//
#include <hip/hip_runtime.h>
#include <math.h>

#define N_NODES 50000
#define N_EDGES 800000
#define ETOT    (N_EDGES + N_NODES)
#define DH      128
#define NH      4
#define LN_EPS  1e-5f
#define NBLK    ((N_NODES + 255) / 256)   // 196 scan blocks
#define LOG2E   1.4426950408889634f

typedef __attribute__((ext_vector_type(8))) short short8;
typedef __attribute__((ext_vector_type(4))) float f32x4;
typedef __attribute__((ext_vector_type(4))) unsigned short ushort4v;

// ---------- fp32 -> bf16 (RNE) split helpers ----------
__device__ __forceinline__ unsigned short f2bf(float f) {
    unsigned u = __float_as_uint(f);
    u += 0x7FFFu + ((u >> 16) & 1u);
    return (unsigned short)(u >> 16);
}
__device__ __forceinline__ float bf2f(unsigned short h) {
    return __uint_as_float(((unsigned)h) << 16);
}

// ---------- fast exact-GELU (A&S 7.1.26 erf, max err ~1.5e-7) ----------
__device__ __forceinline__ float gelu_exact(float x) {
    const float z  = x * 0.70710678118654752f;
    const float az = fabsf(z);
    const float tt = __builtin_amdgcn_rcpf(fmaf(0.3275911f, az, 1.f));
    float p = fmaf(1.061405429f, tt, -1.453152027f);
    p = fmaf(p, tt, 1.421413741f);
    p = fmaf(p, tt, -0.284496736f);
    p = fmaf(p, tt, 0.254829592f);
    p = p * tt;
    const float ez = exp2f(-(z * z) * LOG2E);
    float er = fmaf(-p, ez, 1.f);
    er = copysignf(er, z);
    return x * fmaf(0.5f, er, 0.5f);
}

// ========== pack 5 weight matrices into MFMA B-fragment order (hi/lo) ==========
__global__ __launch_bounds__(256) void pack_w_kernel(
    const float* __restrict__ W0, const float* __restrict__ W1,
    const float* __restrict__ W2, const float* __restrict__ W3,
    const float* __restrict__ W4,
    short* __restrict__ hi, short* __restrict__ lo)
{
    const int idx = blockIdx.x * 256 + threadIdx.x;   // 0..81919
    const int mat = idx >> 14;
    const int rem = idx & 16383;
    const int t = rem >> 12, c = (rem >> 9) & 7, l = (rem >> 3) & 63, j = rem & 7;
    const int k = t * 32 + (l >> 4) * 8 + j;
    const int n = c * 16 + (l & 15);
    const float* W = (mat == 0) ? W0 : (mat == 1) ? W1 : (mat == 2) ? W2
                   : (mat == 3) ? W3 : W4;
    const float v = W[k * DH + n];
    const unsigned short h = f2bf(v);
    hi[idx] = (short)h;
    lo[idx] = (short)f2bf(v - bf2f(h));
}

// ========== split-bf16 MFMA GEMM ==========
// blockIdx.y == 0: Y = A@Wl+bl -> bf16 store (the gathered operand)
// blockIdx.y == 1: Y = A@Wr+br -> fp32 store
#define MTILE 128
__global__ __launch_bounds__(256) void gemm_mfma_kernel(
    const float* __restrict__ A, int m_rows,
    const short* __restrict__ WhiL, const short* __restrict__ WloL,
    const float* __restrict__ biasL, unsigned short* __restrict__ YLb,
    const short* __restrict__ WhiR, const short* __restrict__ WloR,
    const float* __restrict__ biasR, float* __restrict__ YR)
{
    const int w    = threadIdx.x >> 6;
    const int lane = threadIdx.x & 63;
    const short* Whi  = blockIdx.y ? WhiR  : WhiL;
    const short* Wlo  = blockIdx.y ? WloR  : WloL;
    const float* bias = blockIdx.y ? biasR : biasL;

    const int rows0 = blockIdx.x * MTILE + w * 32;
    const int g  = lane >> 4;
    const int rl = lane & 15;

    f32x4 acc[2][8];
    #pragma unroll
    for (int r = 0; r < 2; ++r)
        #pragma unroll
        for (int c = 0; c < 8; ++c)
            acc[r][c] = (f32x4){0.f, 0.f, 0.f, 0.f};

    for (int t = 0; t < 4; ++t) {
        short8 ahi[2], alo[2];
        #pragma unroll
        for (int r = 0; r < 2; ++r) {
            int arow = rows0 + 16 * r + rl;
            arow = (arow < m_rows) ? arow : (m_rows - 1);
            const float* ap = A + (size_t)arow * DH + t * 32 + g * 8;
            const float4 f0 = *(const float4*)ap;
            const float4 f1 = *(const float4*)(ap + 4);
            const float fv[8] = {f0.x, f0.y, f0.z, f0.w, f1.x, f1.y, f1.z, f1.w};
            #pragma unroll
            for (int j = 0; j < 8; ++j) {
                const unsigned short h = f2bf(fv[j]);
                ahi[r][j] = (short)h;
                alo[r][j] = (short)f2bf(fv[j] - bf2f(h));
            }
        }
        #pragma unroll
        for (int c = 0; c < 8; ++c) {
            const int fidx = ((t * 8 + c) * 64 + lane) * 8;
            const short8 bhi = *(const short8*)(Whi + fidx);
            const short8 blo = *(const short8*)(Wlo + fidx);
            acc[0][c] = __builtin_amdgcn_mfma_f32_16x16x32_bf16(ahi[0], bhi, acc[0][c], 0, 0, 0);
            acc[1][c] = __builtin_amdgcn_mfma_f32_16x16x32_bf16(ahi[1], bhi, acc[1][c], 0, 0, 0);
            acc[0][c] = __builtin_amdgcn_mfma_f32_16x16x32_bf16(alo[0], bhi, acc[0][c], 0, 0, 0);
            acc[1][c] = __builtin_amdgcn_mfma_f32_16x16x32_bf16(alo[1], bhi, acc[1][c], 0, 0, 0);
            acc[0][c] = __builtin_amdgcn_mfma_f32_16x16x32_bf16(ahi[0], blo, acc[0][c], 0, 0, 0);
            acc[1][c] = __builtin_amdgcn_mfma_f32_16x16x32_bf16(ahi[1], blo, acc[1][c], 0, 0, 0);
        }
    }
    #pragma unroll
    for (int c = 0; c < 8; ++c) {
        const int col = c * 16 + rl;
        const float bb = bias[col];
        #pragma unroll
        for (int r = 0; r < 2; ++r) {
            #pragma unroll
            for (int q = 0; q < 4; ++q) {
                const int row = rows0 + 16 * r + g * 4 + q;
                if (row < m_rows) {
                    const float y = acc[r][c][q] + bb;
                    if (blockIdx.y == 0)
                        YLb[(size_t)row * DH + col] = f2bf(y);
                    else
                        YR[(size_t)row * DH + col] = y;
                }
            }
        }
    }
}

// ========== gemm1 + fused final LayerNorm: out = LN(A@W + b; g, bt) ==========
__global__ __launch_bounds__(256) void gemm1_ln_kernel(
    const float* __restrict__ A, int m_rows,
    const short* __restrict__ Whi, const short* __restrict__ Wlo,
    const float* __restrict__ bias,
    const float* __restrict__ gam, const float* __restrict__ bet,
    float* __restrict__ out)
{
    const int w    = threadIdx.x >> 6;
    const int lane = threadIdx.x & 63;
    const int rows0 = blockIdx.x * MTILE + w * 32;
    const int g  = lane >> 4;
    const int rl = lane & 15;

    f32x4 acc[2][8];
    #pragma unroll
    for (int r = 0; r < 2; ++r)
        #pragma unroll
        for (int c = 0; c < 8; ++c)
            acc[r][c] = (f32x4){0.f, 0.f, 0.f, 0.f};

    for (int t = 0; t < 4; ++t) {
        short8 ahi[2], alo[2];
        #pragma unroll
        for (int r = 0; r < 2; ++r) {
            int arow = rows0 + 16 * r + rl;
            arow = (arow < m_rows) ? arow : (m_rows - 1);
            const float* ap = A + (size_t)arow * DH + t * 32 + g * 8;
            const float4 f0 = *(const float4*)ap;
            const float4 f1 = *(const float4*)(ap + 4);
            const float fv[8] = {f0.x, f0.y, f0.z, f0.w, f1.x, f1.y, f1.z, f1.w};
            #pragma unroll
            for (int j = 0; j < 8; ++j) {
                const unsigned short h = f2bf(fv[j]);
                ahi[r][j] = (short)h;
                alo[r][j] = (short)f2bf(fv[j] - bf2f(h));
            }
        }
        #pragma unroll
        for (int c = 0; c < 8; ++c) {
            const int fidx = ((t * 8 + c) * 64 + lane) * 8;
            const short8 bh = *(const short8*)(Whi + fidx);
            const short8 bl = *(const short8*)(Wlo + fidx);
            acc[0][c] = __builtin_amdgcn_mfma_f32_16x16x32_bf16(ahi[0], bh, acc[0][c], 0, 0, 0);
            acc[1][c] = __builtin_amdgcn_mfma_f32_16x16x32_bf16(ahi[1], bh, acc[1][c], 0, 0, 0);
            acc[0][c] = __builtin_amdgcn_mfma_f32_16x16x32_bf16(alo[0], bh, acc[0][c], 0, 0, 0);
            acc[1][c] = __builtin_amdgcn_mfma_f32_16x16x32_bf16(alo[1], bh, acc[1][c], 0, 0, 0);
            acc[0][c] = __builtin_amdgcn_mfma_f32_16x16x32_bf16(ahi[0], bl, acc[0][c], 0, 0, 0);
            acc[1][c] = __builtin_amdgcn_mfma_f32_16x16x32_bf16(ahi[1], bl, acc[1][c], 0, 0, 0);
        }
    }

    float bb[8], gg[8], bt8[8];
    #pragma unroll
    for (int c = 0; c < 8; ++c) {
        const int col = c * 16 + rl;
        bb[c] = bias[col];  gg[c] = gam[col];  bt8[c] = bet[col];
    }
    #pragma unroll
    for (int r = 0; r < 2; ++r) {
        #pragma unroll
        for (int q = 0; q < 4; ++q) {
            float v[8];
            float s = 0.f, sq = 0.f;
            #pragma unroll
            for (int c = 0; c < 8; ++c) {
                v[c] = acc[r][c][q] + bb[c];
                s  += v[c];
                sq  = fmaf(v[c], v[c], sq);
            }
            #pragma unroll
            for (int off = 1; off < 16; off <<= 1) {
                s  += __shfl_xor(s,  off);
                sq += __shfl_xor(sq, off);
            }
            const float mu   = s * (1.f / 128.f);
            const float var  = sq * (1.f / 128.f) - mu * mu;
            const float rstd = rsqrtf(var + LN_EPS);
            const int row = rows0 + 16 * r + g * 4 + q;
            if (row < m_rows) {
                #pragma unroll
                for (int c = 0; c < 8; ++c)
                    out[(size_t)row * DH + c * 16 + rl] =
                        (v[c] - mu) * rstd * gg[c] + bt8[c];
            }
        }
    }
}

// ========================= CSR construction =========================
__global__ __launch_bounds__(256) void degree_kernel(
    const int* __restrict__ eidx, int* __restrict__ deg)
{
    const int i = blockIdx.x * 256 + threadIdx.x;
    if (i >= ETOT) return;
    const int d = (i < N_EDGES) ? eidx[N_EDGES + i] : (i - N_EDGES);
    atomicAdd(&deg[d], 1);
}

__global__ __launch_bounds__(256) void block_sum_kernel(
    const int* __restrict__ deg, int* __restrict__ bsum)
{
    const int i    = blockIdx.x * 256 + threadIdx.x;
    const int lane = threadIdx.x & 63;
    const int wid  = threadIdx.x >> 6;
    int v = (i < N_NODES) ? deg[i] : 0;
    #pragma unroll
    for (int off = 32; off; off >>= 1) v += __shfl_xor(v, off);
    __shared__ int ws[4];
    if (lane == 0) ws[wid] = v;
    __syncthreads();
    if (threadIdx.x == 0) bsum[blockIdx.x] = ws[0] + ws[1] + ws[2] + ws[3];
}

__global__ __launch_bounds__(256) void scan_partials_kernel(
    const int* __restrict__ bsum, int* __restrict__ boff)
{
    const int t    = threadIdx.x;
    const int lane = t & 63;
    const int wid  = t >> 6;
    int v = (t < NBLK) ? bsum[t] : 0;
    int inc = v;
    #pragma unroll
    for (int off = 1; off < 64; off <<= 1) {
        int u = __shfl_up(inc, off);
        if (lane >= off) inc += u;
    }
    __shared__ int ws[4];
    if (lane == 63) ws[wid] = inc;
    __syncthreads();
    int add = 0;
    for (int w = 0; w < wid; ++w) add += ws[w];
    if (t < NBLK) boff[t] = add + inc - v;
}

__global__ __launch_bounds__(256) void rowptr_kernel(
    const int* __restrict__ deg, const int* __restrict__ boff,
    int* __restrict__ rowptr, int* __restrict__ cursor)
{
    const int i    = blockIdx.x * 256 + threadIdx.x;
    const int lane = threadIdx.x & 63;
    const int wid  = threadIdx.x >> 6;
    int v = (i < N_NODES) ? deg[i] : 0;
    int inc = v;
    #pragma unroll
    for (int off = 1; off < 64; off <<= 1) {
        int u = __shfl_up(inc, off);
        if (lane >= off) inc += u;
    }
    __shared__ int ws[4];
    if (lane == 63) ws[wid] = inc;
    __syncthreads();
    int add = boff[blockIdx.x];
    for (int w = 0; w < wid; ++w) add += ws[w];
    if (i < N_NODES) {
        const int ex = add + inc - v;
        rowptr[i] = ex;
        cursor[i] = ex;
    }
}

__global__ __launch_bounds__(256) void scatter_kernel(
    const int* __restrict__ eidx, int* __restrict__ cursor,
    int* __restrict__ csr_src)
{
    const int i = blockIdx.x * 256 + threadIdx.x;
    if (i >= ETOT) return;
    int s, d;
    if (i < N_EDGES) { s = eidx[i]; d = eidx[N_EDGES + i]; }
    else             { s = d = i - N_EDGES; }
    const int slot = atomicAdd(&cursor[d], 1);
    csr_src[slot] = s;
}

// ====== fused per-node GAT: bf16 gathers, no-max base-2 softmax ======
// wave = one dst node; 32 lanes/edge, 4 ch/lane, 2 edge slots (halves)
__global__ __launch_bounds__(256) void gat_node_kernel(
    const int* __restrict__ rowptr, const int* __restrict__ deg,
    const int* __restrict__ csr_src,
    const unsigned short* __restrict__ xlb, const float* __restrict__ xr,
    const float* __restrict__ att, const float* __restrict__ bias,
    const float* __restrict__ gam, const float* __restrict__ bet,
    float* __restrict__ out)
{
    const int n    = blockIdx.x * 4 + (threadIdx.x >> 6);
    const int lane = threadIdx.x & 63;
    if (n >= N_NODES) return;
    const int half = lane >> 5;
    const int cl   = lane & 31;
    const int c0   = cl * 4;

    const float4 xrv = *(const float4*)(xr + (size_t)n * DH + c0);
    const float4 at  = *(const float4*)(att + c0);
    // leaky_relu(t) = 0.6t + 0.4|t|; fold log2(e) for base-2 exp
    float4 a6, a4;
    a6.x = at.x * (0.6f * LOG2E); a6.y = at.y * (0.6f * LOG2E);
    a6.z = at.z * (0.6f * LOG2E); a6.w = at.w * (0.6f * LOG2E);
    a4.x = at.x * (0.4f * LOG2E); a4.y = at.y * (0.4f * LOG2E);
    a4.z = at.z * (0.4f * LOG2E); a4.w = at.w * (0.4f * LOG2E);

    float dsum = 0.f;
    float4 p = {0.f, 0.f, 0.f, 0.f};

    const int beg = rowptr[n];
    const int end = beg + deg[n];

    for (int e = beg; e < end; e += 4) {
        const int eb = e + 2 * half;
        const bool v0 = (eb     < end);
        const bool v1 = (eb + 1 < end);
        const int s0 = v0 ? csr_src[eb]     : 0;
        const int s1 = v1 ? csr_src[eb + 1] : 0;
        const ushort4v u0 = *(const ushort4v*)(xlb + (unsigned)s0 * DH + c0);
        const ushort4v u1 = *(const ushort4v*)(xlb + (unsigned)s1 * DH + c0);
        float4 x0, x1;
        x0.x = bf2f(u0[0]); x0.y = bf2f(u0[1]); x0.z = bf2f(u0[2]); x0.w = bf2f(u0[3]);
        x1.x = bf2f(u1[0]); x1.y = bf2f(u1[1]); x1.z = bf2f(u1[2]); x1.w = bf2f(u1[3]);

        float t, l0 = 0.f, l1 = 0.f;
        t = x0.x + xrv.x; l0 = fmaf(a6.x, t, fmaf(a4.x, fabsf(t), l0));
        t = x0.y + xrv.y; l0 = fmaf(a6.y, t, fmaf(a4.y, fabsf(t), l0));
        t = x0.z + xrv.z; l0 = fmaf(a6.z, t, fmaf(a4.z, fabsf(t), l0));
        t = x0.w + xrv.w; l0 = fmaf(a6.w, t, fmaf(a4.w, fabsf(t), l0));
        t = x1.x + xrv.x; l1 = fmaf(a6.x, t, fmaf(a4.x, fabsf(t), l1));
        t = x1.y + xrv.y; l1 = fmaf(a6.y, t, fmaf(a4.y, fabsf(t), l1));
        t = x1.z + xrv.z; l1 = fmaf(a6.z, t, fmaf(a4.z, fabsf(t), l1));
        t = x1.w + xrv.w; l1 = fmaf(a6.w, t, fmaf(a4.w, fabsf(t), l1));

        // head reduce: 8 lanes per head
        l0 += __shfl_xor(l0, 1);  l1 += __shfl_xor(l1, 1);
        l0 += __shfl_xor(l0, 2);  l1 += __shfl_xor(l1, 2);
        l0 += __shfl_xor(l0, 4);  l1 += __shfl_xor(l1, 4);

        // masked edges contribute exp2(-inf) = 0
        l0 = v0 ? l0 : -INFINITY;
        l1 = v1 ? l1 : -INFINITY;
        const float w0 = exp2f(l0);
        const float w1 = exp2f(l1);
        dsum += w0 + w1;
        p.x = fmaf(x0.x, w0, p.x);  p.x = fmaf(x1.x, w1, p.x);
        p.y = fmaf(x0.y, w0, p.y);  p.y = fmaf(x1.y, w1, p.y);
        p.z = fmaf(x0.z, w0, p.z);  p.z = fmaf(x1.z, w1, p.z);
        p.w = fmaf(x0.w, w0, p.w);  p.w = fmaf(x1.w, w1, p.w);
    }

    // cross-half merge (lane ^ 32): plain sums
    dsum += __shfl_xor(dsum, 32);
    p.x  += __shfl_xor(p.x, 32);
    p.y  += __shfl_xor(p.y, 32);
    p.z  += __shfl_xor(p.z, 32);
    p.w  += __shfl_xor(p.w, 32);

    const float inv = 1.f / dsum;
    const float4 bi = *(const float4*)(bias + c0);
    float v0 = p.x * inv + bi.x;
    float v1 = p.y * inv + bi.y;
    float v2 = p.z * inv + bi.z;
    float v3 = p.w * inv + bi.w;

    // LayerNorm over 128 ch = 32 lanes x 4 (xor 1..16 stays within half)
    float s2 = v0 + v1 + v2 + v3;
    float sq = v0*v0 + v1*v1 + v2*v2 + v3*v3;
    #pragma unroll
    for (int off = 16; off; off >>= 1) {
        s2 += __shfl_xor(s2, off);
        sq += __shfl_xor(sq, off);
    }
    const float mu   = s2 * (1.f / 128.f);
    const float var  = sq * (1.f / 128.f) - mu * mu;
    const float rstd = rsqrtf(var + LN_EPS);

    const float4 gm = *(const float4*)(gam + c0);
    const float4 bt = *(const float4*)(bet + c0);
    float y0 = gelu_exact((v0 - mu) * rstd * gm.x + bt.x);
    float y1 = gelu_exact((v1 - mu) * rstd * gm.y + bt.y);
    float y2 = gelu_exact((v2 - mu) * rstd * gm.z + bt.z);
    float y3 = gelu_exact((v3 - mu) * rstd * gm.w + bt.w);

    if (half == 0) {
        float4 yv = {y0, y1, y2, y3};
        *(float4*)(out + (size_t)n * DH + c0) = yv;
    }
}

extern "C" void kernel_launch(void* const* d_in, const int* in_sizes, int n_in,
                              void* d_out, int out_size, void* d_ws, size_t ws_size,
                              hipStream_t stream)
{
    const float* x    = (const float*)d_in[0];
    const int*   eidx = (const int*)  d_in[1];

    const float* Wl[2]   = { (const float*)d_in[2],  (const float*)d_in[10] };
    const float* bl[2]   = { (const float*)d_in[3],  (const float*)d_in[11] };
    const float* Wr[2]   = { (const float*)d_in[4],  (const float*)d_in[12] };
    const float* br[2]   = { (const float*)d_in[5],  (const float*)d_in[13] };
    const float* att[2]  = { (const float*)d_in[6],  (const float*)d_in[14] };
    const float* bias[2] = { (const float*)d_in[7],  (const float*)d_in[15] };
    const float* gam[2]  = { (const float*)d_in[8],  (const float*)d_in[16] };
    const float* bet[2]  = { (const float*)d_in[9],  (const float*)d_in[17] };
    const float* Wout    = (const float*)d_in[18];
    const float* bout    = (const float*)d_in[19];
    const float* gout    = (const float*)d_in[20];
    const float* boutln  = (const float*)d_in[21];

    float* out = (float*)d_out;

    const size_t NF = (size_t)N_NODES * DH;
    float*          xr   = (float*)d_ws;            // NF fp32
    unsigned short* xlb  = (unsigned short*)(xr + NF);  // NF bf16
    float*          h1   = (float*)(xlb + NF);      // NF fp32
    float*          h2   = h1 + NF;
    int*   csr_src = (int*)(h2 + NF);
    int*   deg     = csr_src + ETOT + 8;   // +8 pad
    int*   rowptr  = deg + N_NODES;
    int*   cursor  = rowptr + N_NODES;
    int*   bsum    = cursor + N_NODES;
    int*   boff    = bsum + NBLK;
    short* whi     = (short*)(boff + NBLK);   // 5 * 16384 shorts
    short* wlo     = whi + 5 * 16384;

    const int etBlocks   = (ETOT + 255) / 256;
    const int nodeBlocks = N_NODES / 4;
    const int gemmBlocks = (N_NODES + MTILE - 1) / MTILE;   // 391

    #define WP(i) (whi + (i) * 16384), (wlo + (i) * 16384)

    // ---- CSR (deterministic rebuild every call) ----
    hipMemsetAsync(deg, 0, N_NODES * sizeof(int), stream);
    degree_kernel       <<<etBlocks, 256, 0, stream>>>(eidx, deg);
    block_sum_kernel    <<<NBLK, 256, 0, stream>>>(deg, bsum);
    scan_partials_kernel<<<1, 256, 0, stream>>>(bsum, boff);
    rowptr_kernel       <<<NBLK, 256, 0, stream>>>(deg, boff, rowptr, cursor);
    scatter_kernel      <<<etBlocks, 256, 0, stream>>>(eidx, cursor, csr_src);

    // ---- pack all 5 weight matrices ----
    pack_w_kernel<<<320, 256, 0, stream>>>(Wl[0], Wr[0], Wl[1], Wr[1], Wout, whi, wlo);

    // ---- layer 0 ----
    gemm_mfma_kernel<<<dim3(gemmBlocks, 2), 256, 0, stream>>>(
        x, N_NODES, WP(0), bl[0], xlb, WP(1), br[0], xr);
    gat_node_kernel<<<nodeBlocks, 256, 0, stream>>>(rowptr, deg, csr_src, xlb, xr,
                                                    att[0], bias[0], gam[0], bet[0], h1);
    // ---- layer 1 ----
    gemm_mfma_kernel<<<dim3(gemmBlocks, 2), 256, 0, stream>>>(
        h1, N_NODES, WP(2), bl[1], xlb, WP(3), br[1], xr);
    gat_node_kernel<<<nodeBlocks, 256, 0, stream>>>(rowptr, deg, csr_src, xlb, xr,
                                                    att[1], bias[1], gam[1], bet[1], h2);

    // ---- output projection + fused final LayerNorm ----
    gemm1_ln_kernel<<<gemmBlocks, 256, 0, stream>>>(
        h2, N_NODES, WP(4), bout, gout, boutln, out);
}

// Round 9
// 306.564 us; speedup vs baseline: 1.2747x; 1.0583x over previous
//
#include <hip/hip_runtime.h>
#include <math.h>

#define N_NODES 50000
#define N_EDGES 800000
#define ETOT    (N_EDGES + N_NODES)
#define DH      128
#define NH      4
#define LN_EPS  1e-5f
#define NBLK    ((N_NODES + 255) / 256)   // 196 scan blocks
#define LOG2E   1.4426950408889634f

typedef __attribute__((ext_vector_type(8))) short short8;
typedef __attribute__((ext_vector_type(8))) unsigned short ushort8v;
typedef __attribute__((ext_vector_type(4))) float f32x4;
typedef __attribute__((ext_vector_type(4))) unsigned uint4v;

// ---------- fp32 -> bf16 (RNE) helpers ----------
__device__ __forceinline__ unsigned short f2bf(float f) {
    unsigned u = __float_as_uint(f);
    u += 0x7FFFu + ((u >> 16) & 1u);
    return (unsigned short)(u >> 16);
}
__device__ __forceinline__ float bf2f(unsigned short h) {
    return __uint_as_float(((unsigned)h) << 16);
}
// packed split: two fp32 -> one u32 of 2 bf16 (hi) + residual u32 (lo)
__device__ __forceinline__ void split_pair(float a, float b, unsigned& hi, unsigned& lo) {
    unsigned h;
    asm("v_cvt_pk_bf16_f32 %0, %1, %2" : "=v"(h) : "v"(a), "v"(b));
    const float ra = a - __uint_as_float(h << 16);
    const float rb = b - __uint_as_float(h & 0xffff0000u);
    unsigned l;
    asm("v_cvt_pk_bf16_f32 %0, %1, %2" : "=v"(l) : "v"(ra), "v"(rb));
    hi = h; lo = l;
}

// ---------- fast exact-GELU (A&S 7.1.26 erf, max err ~1.5e-7) ----------
__device__ __forceinline__ float gelu_exact(float x) {
    const float z  = x * 0.70710678118654752f;
    const float az = fabsf(z);
    const float tt = __builtin_amdgcn_rcpf(fmaf(0.3275911f, az, 1.f));
    float p = fmaf(1.061405429f, tt, -1.453152027f);
    p = fmaf(p, tt, 1.421413741f);
    p = fmaf(p, tt, -0.284496736f);
    p = fmaf(p, tt, 0.254829592f);
    p = p * tt;
    const float ez = exp2f(-(z * z) * LOG2E);
    float er = fmaf(-p, ez, 1.f);
    er = copysignf(er, z);
    return x * fmaf(0.5f, er, 0.5f);
}

// ========== pack 5 weight matrices into MFMA B-fragment order (hi/lo) ==========
__global__ __launch_bounds__(256) void pack_w_kernel(
    const float* __restrict__ W0, const float* __restrict__ W1,
    const float* __restrict__ W2, const float* __restrict__ W3,
    const float* __restrict__ W4,
    short* __restrict__ hi, short* __restrict__ lo)
{
    const int idx = blockIdx.x * 256 + threadIdx.x;   // 0..81919
    const int mat = idx >> 14;
    const int rem = idx & 16383;
    const int t = rem >> 12, c = (rem >> 9) & 7, l = (rem >> 3) & 63, j = rem & 7;
    const int k = t * 32 + (l >> 4) * 8 + j;
    const int n = c * 16 + (l & 15);
    const float* W = (mat == 0) ? W0 : (mat == 1) ? W1 : (mat == 2) ? W2
                   : (mat == 3) ? W3 : W4;
    const float v = W[k * DH + n];
    const unsigned short h = f2bf(v);
    hi[idx] = (short)h;
    lo[idx] = (short)f2bf(v - bf2f(h));
}

// ========== split-bf16 MFMA GEMM; bf16 outputs ==========
// blockIdx.y==0: YL = A@Wl+bl ; blockIdx.y==1: YR = A@Wr+br  (both bf16 stores)
#define MTILE 128
__global__ __launch_bounds__(256) void gemm_mfma_kernel(
    const float* __restrict__ A, int m_rows,
    const short* __restrict__ WhiL, const short* __restrict__ WloL,
    const float* __restrict__ biasL, unsigned short* __restrict__ YL,
    const short* __restrict__ WhiR, const short* __restrict__ WloR,
    const float* __restrict__ biasR, unsigned short* __restrict__ YR)
{
    const int w    = threadIdx.x >> 6;
    const int lane = threadIdx.x & 63;
    const short* Whi  = blockIdx.y ? WhiR  : WhiL;
    const short* Wlo  = blockIdx.y ? WloR  : WloL;
    const float* bias = blockIdx.y ? biasR : biasL;
    unsigned short* Y = blockIdx.y ? YR    : YL;

    const int rows0 = blockIdx.x * MTILE + w * 32;
    const int g  = lane >> 4;
    const int rl = lane & 15;

    f32x4 acc[2][8];
    #pragma unroll
    for (int r = 0; r < 2; ++r)
        #pragma unroll
        for (int c = 0; c < 8; ++c)
            acc[r][c] = (f32x4){0.f, 0.f, 0.f, 0.f};

    for (int t = 0; t < 4; ++t) {
        short8 ahi[2], alo[2];
        #pragma unroll
        for (int r = 0; r < 2; ++r) {
            int arow = rows0 + 16 * r + rl;
            arow = (arow < m_rows) ? arow : (m_rows - 1);
            const float* ap = A + (size_t)arow * DH + t * 32 + g * 8;
            const float4 f0 = *(const float4*)ap;
            const float4 f1 = *(const float4*)(ap + 4);
            unsigned h0, l0, h1, l1, h2, l2, h3, l3;
            split_pair(f0.x, f0.y, h0, l0);
            split_pair(f0.z, f0.w, h1, l1);
            split_pair(f1.x, f1.y, h2, l2);
            split_pair(f1.z, f1.w, h3, l3);
            ahi[r] = __builtin_bit_cast(short8, (uint4v){h0, h1, h2, h3});
            alo[r] = __builtin_bit_cast(short8, (uint4v){l0, l1, l2, l3});
        }
        #pragma unroll
        for (int c = 0; c < 8; ++c) {
            const int fidx = ((t * 8 + c) * 64 + lane) * 8;
            const short8 bhi = *(const short8*)(Whi + fidx);
            const short8 blo = *(const short8*)(Wlo + fidx);
            acc[0][c] = __builtin_amdgcn_mfma_f32_16x16x32_bf16(ahi[0], bhi, acc[0][c], 0, 0, 0);
            acc[1][c] = __builtin_amdgcn_mfma_f32_16x16x32_bf16(ahi[1], bhi, acc[1][c], 0, 0, 0);
            acc[0][c] = __builtin_amdgcn_mfma_f32_16x16x32_bf16(alo[0], bhi, acc[0][c], 0, 0, 0);
            acc[1][c] = __builtin_amdgcn_mfma_f32_16x16x32_bf16(alo[1], bhi, acc[1][c], 0, 0, 0);
            acc[0][c] = __builtin_amdgcn_mfma_f32_16x16x32_bf16(ahi[0], blo, acc[0][c], 0, 0, 0);
            acc[1][c] = __builtin_amdgcn_mfma_f32_16x16x32_bf16(ahi[1], blo, acc[1][c], 0, 0, 0);
        }
    }
    #pragma unroll
    for (int c = 0; c < 8; ++c) {
        const int col = c * 16 + rl;
        const float bb = bias[col];
        #pragma unroll
        for (int r = 0; r < 2; ++r) {
            #pragma unroll
            for (int q = 0; q < 4; ++q) {
                const int row = rows0 + 16 * r + g * 4 + q;
                if (row < m_rows)
                    Y[(size_t)row * DH + col] = f2bf(acc[r][c][q] + bb);
            }
        }
    }
}

// ========== gemm1 + fused final LayerNorm: out = LN(A@W + b; g, bt) ==========
__global__ __launch_bounds__(256) void gemm1_ln_kernel(
    const float* __restrict__ A, int m_rows,
    const short* __restrict__ Whi, const short* __restrict__ Wlo,
    const float* __restrict__ bias,
    const float* __restrict__ gam, const float* __restrict__ bet,
    float* __restrict__ out)
{
    const int w    = threadIdx.x >> 6;
    const int lane = threadIdx.x & 63;
    const int rows0 = blockIdx.x * MTILE + w * 32;
    const int g  = lane >> 4;
    const int rl = lane & 15;

    f32x4 acc[2][8];
    #pragma unroll
    for (int r = 0; r < 2; ++r)
        #pragma unroll
        for (int c = 0; c < 8; ++c)
            acc[r][c] = (f32x4){0.f, 0.f, 0.f, 0.f};

    for (int t = 0; t < 4; ++t) {
        short8 ahi[2], alo[2];
        #pragma unroll
        for (int r = 0; r < 2; ++r) {
            int arow = rows0 + 16 * r + rl;
            arow = (arow < m_rows) ? arow : (m_rows - 1);
            const float* ap = A + (size_t)arow * DH + t * 32 + g * 8;
            const float4 f0 = *(const float4*)ap;
            const float4 f1 = *(const float4*)(ap + 4);
            unsigned h0, l0, h1, l1, h2, l2, h3, l3;
            split_pair(f0.x, f0.y, h0, l0);
            split_pair(f0.z, f0.w, h1, l1);
            split_pair(f1.x, f1.y, h2, l2);
            split_pair(f1.z, f1.w, h3, l3);
            ahi[r] = __builtin_bit_cast(short8, (uint4v){h0, h1, h2, h3});
            alo[r] = __builtin_bit_cast(short8, (uint4v){l0, l1, l2, l3});
        }
        #pragma unroll
        for (int c = 0; c < 8; ++c) {
            const int fidx = ((t * 8 + c) * 64 + lane) * 8;
            const short8 bh = *(const short8*)(Whi + fidx);
            const short8 bl = *(const short8*)(Wlo + fidx);
            acc[0][c] = __builtin_amdgcn_mfma_f32_16x16x32_bf16(ahi[0], bh, acc[0][c], 0, 0, 0);
            acc[1][c] = __builtin_amdgcn_mfma_f32_16x16x32_bf16(ahi[1], bh, acc[1][c], 0, 0, 0);
            acc[0][c] = __builtin_amdgcn_mfma_f32_16x16x32_bf16(alo[0], bh, acc[0][c], 0, 0, 0);
            acc[1][c] = __builtin_amdgcn_mfma_f32_16x16x32_bf16(alo[1], bh, acc[1][c], 0, 0, 0);
            acc[0][c] = __builtin_amdgcn_mfma_f32_16x16x32_bf16(ahi[0], bl, acc[0][c], 0, 0, 0);
            acc[1][c] = __builtin_amdgcn_mfma_f32_16x16x32_bf16(ahi[1], bl, acc[1][c], 0, 0, 0);
        }
    }

    float bb[8], gg[8], bt8[8];
    #pragma unroll
    for (int c = 0; c < 8; ++c) {
        const int col = c * 16 + rl;
        bb[c] = bias[col];  gg[c] = gam[col];  bt8[c] = bet[col];
    }
    #pragma unroll
    for (int r = 0; r < 2; ++r) {
        #pragma unroll
        for (int q = 0; q < 4; ++q) {
            float v[8];
            float s = 0.f, sq = 0.f;
            #pragma unroll
            for (int c = 0; c < 8; ++c) {
                v[c] = acc[r][c][q] + bb[c];
                s  += v[c];
                sq  = fmaf(v[c], v[c], sq);
            }
            #pragma unroll
            for (int off = 1; off < 16; off <<= 1) {
                s  += __shfl_xor(s,  off);
                sq += __shfl_xor(sq, off);
            }
            const float mu   = s * (1.f / 128.f);
            const float var  = sq * (1.f / 128.f) - mu * mu;
            const float rstd = rsqrtf(var + LN_EPS);
            const int row = rows0 + 16 * r + g * 4 + q;
            if (row < m_rows) {
                #pragma unroll
                for (int c = 0; c < 8; ++c)
                    out[(size_t)row * DH + c * 16 + rl] =
                        (v[c] - mu) * rstd * gg[c] + bt8[c];
            }
        }
    }
}

// ========================= CSR construction =========================
__global__ __launch_bounds__(256) void degree_kernel(
    const int* __restrict__ eidx, int* __restrict__ deg)
{
    const int i = blockIdx.x * 256 + threadIdx.x;
    if (i >= ETOT) return;
    const int d = (i < N_EDGES) ? eidx[N_EDGES + i] : (i - N_EDGES);
    atomicAdd(&deg[d], 1);
}

__global__ __launch_bounds__(256) void block_sum_kernel(
    const int* __restrict__ deg, int* __restrict__ bsum)
{
    const int i    = blockIdx.x * 256 + threadIdx.x;
    const int lane = threadIdx.x & 63;
    const int wid  = threadIdx.x >> 6;
    int v = (i < N_NODES) ? deg[i] : 0;
    #pragma unroll
    for (int off = 32; off; off >>= 1) v += __shfl_xor(v, off);
    __shared__ int ws[4];
    if (lane == 0) ws[wid] = v;
    __syncthreads();
    if (threadIdx.x == 0) bsum[blockIdx.x] = ws[0] + ws[1] + ws[2] + ws[3];
}

__global__ __launch_bounds__(256) void scan_partials_kernel(
    const int* __restrict__ bsum, int* __restrict__ boff)
{
    const int t    = threadIdx.x;
    const int lane = t & 63;
    const int wid  = t >> 6;
    int v = (t < NBLK) ? bsum[t] : 0;
    int inc = v;
    #pragma unroll
    for (int off = 1; off < 64; off <<= 1) {
        int u = __shfl_up(inc, off);
        if (lane >= off) inc += u;
    }
    __shared__ int ws[4];
    if (lane == 63) ws[wid] = inc;
    __syncthreads();
    int add = 0;
    for (int w = 0; w < wid; ++w) add += ws[w];
    if (t < NBLK) boff[t] = add + inc - v;
}

__global__ __launch_bounds__(256) void rowptr_kernel(
    const int* __restrict__ deg, const int* __restrict__ boff,
    int* __restrict__ rowptr, int* __restrict__ cursor)
{
    const int i    = blockIdx.x * 256 + threadIdx.x;
    const int lane = threadIdx.x & 63;
    const int wid  = threadIdx.x >> 6;
    int v = (i < N_NODES) ? deg[i] : 0;
    int inc = v;
    #pragma unroll
    for (int off = 1; off < 64; off <<= 1) {
        int u = __shfl_up(inc, off);
        if (lane >= off) inc += u;
    }
    __shared__ int ws[4];
    if (lane == 63) ws[wid] = inc;
    __syncthreads();
    int add = boff[blockIdx.x];
    for (int w = 0; w < wid; ++w) add += ws[w];
    if (i < N_NODES) {
        const int ex = add + inc - v;
        rowptr[i] = ex;
        cursor[i] = ex;
    }
}

__global__ __launch_bounds__(256) void scatter_kernel(
    const int* __restrict__ eidx, int* __restrict__ cursor,
    int* __restrict__ csr_src)
{
    const int i = blockIdx.x * 256 + threadIdx.x;
    if (i >= ETOT) return;
    int s, d;
    if (i < N_EDGES) { s = eidx[i]; d = eidx[N_EDGES + i]; }
    else             { s = d = i - N_EDGES; }
    const int slot = atomicAdd(&cursor[d], 1);
    csr_src[slot] = s;
}

// ====== fused per-node GAT: 16 lanes/edge (8 bf16 ch), prefetch, no-max softmax ======
__global__ __launch_bounds__(256) void gat_node_kernel(
    const int* __restrict__ rowptr, const int* __restrict__ deg,
    const int* __restrict__ csr_src,
    const unsigned short* __restrict__ xlb, const unsigned short* __restrict__ xrb,
    const float* __restrict__ att, const float* __restrict__ bias,
    const float* __restrict__ gam, const float* __restrict__ bet,
    float* __restrict__ out)
{
    const int n    = blockIdx.x * 4 + (threadIdx.x >> 6);
    const int lane = threadIdx.x & 63;
    if (n >= N_NODES) return;
    const int q  = lane >> 4;       // edge slot 0..3
    const int r  = lane & 15;       // channel group
    const int c0 = r * 8;

    // xr row (bf16) -> 8 fp32
    const ushort8v ur = *(const ushort8v*)(xrb + (size_t)n * DH + c0);
    float xrv[8];
    #pragma unroll
    for (int j = 0; j < 8; ++j) xrv[j] = bf2f(ur[j]);

    // att coefficients: leaky_relu(t) = 0.6t + 0.4|t|, fold log2(e)
    float a6[8], a4[8];
    #pragma unroll
    for (int j = 0; j < 8; ++j) {
        const float a = att[c0 + j];
        a6[j] = a * (0.6f * LOG2E);
        a4[j] = a * (0.4f * LOG2E);
    }

    float dsum = 0.f;
    float p[8];
    #pragma unroll
    for (int j = 0; j < 8; ++j) p[j] = 0.f;

    const int beg = rowptr[n];
    const int end = beg + deg[n];

    // prefetch first edge for this slot
    int e = beg;
    bool vcur = (e + q) < end;
    int s = vcur ? csr_src[e + q] : 0;
    ushort8v u = *(const ushort8v*)(xlb + (size_t)s * DH + c0);

    while (e < end) {
        const int en = e + 4;
        ushort8v unext = u;
        bool vnext = false;
        if (en < end) {   // wave-uniform
            vnext = (en + q) < end;
            const int sn = vnext ? csr_src[en + q] : 0;
            unext = *(const ushort8v*)(xlb + (size_t)sn * DH + c0);
        }
        // compute current
        float x[8];
        #pragma unroll
        for (int j = 0; j < 8; ++j) x[j] = bf2f(u[j]);
        float l = 0.f;
        #pragma unroll
        for (int j = 0; j < 8; ++j) {
            const float t = x[j] + xrv[j];
            l = fmaf(a6[j], t, fmaf(a4[j], fabsf(t), l));
        }
        // head reduce: 4 lanes per head (head = r>>2)
        l += __shfl_xor(l, 1);
        l += __shfl_xor(l, 2);
        l = vcur ? l : -INFINITY;
        const float w = exp2f(l);
        dsum += w;
        #pragma unroll
        for (int j = 0; j < 8; ++j) p[j] = fmaf(x[j], w, p[j]);

        u = unext; vcur = vnext; e = en;
    }

    // merge the 4 edge slots (quarters): xor 16, 32
    dsum += __shfl_xor(dsum, 16);
    dsum += __shfl_xor(dsum, 32);
    #pragma unroll
    for (int j = 0; j < 8; ++j) {
        p[j] += __shfl_xor(p[j], 16);
        p[j] += __shfl_xor(p[j], 32);
    }

    const float inv = 1.f / dsum;
    float v[8];
    float s2 = 0.f, sq = 0.f;
    #pragma unroll
    for (int j = 0; j < 8; ++j) {
        v[j] = p[j] * inv + bias[c0 + j];
        s2 += v[j];
        sq  = fmaf(v[j], v[j], sq);
    }
    // LN reduce across the 16 channel-groups (quarters are replicas)
    #pragma unroll
    for (int off = 1; off < 16; off <<= 1) {
        s2 += __shfl_xor(s2, off);
        sq += __shfl_xor(sq, off);
    }
    const float mu   = s2 * (1.f / 128.f);
    const float var  = sq * (1.f / 128.f) - mu * mu;
    const float rstd = rsqrtf(var + LN_EPS);

    if (q == 0) {
        float y[8];
        #pragma unroll
        for (int j = 0; j < 8; ++j)
            y[j] = gelu_exact((v[j] - mu) * rstd * gam[c0 + j] + bet[c0 + j]);
        float4 y0 = {y[0], y[1], y[2], y[3]};
        float4 y1 = {y[4], y[5], y[6], y[7]};
        *(float4*)(out + (size_t)n * DH + c0)     = y0;
        *(float4*)(out + (size_t)n * DH + c0 + 4) = y1;
    }
}

extern "C" void kernel_launch(void* const* d_in, const int* in_sizes, int n_in,
                              void* d_out, int out_size, void* d_ws, size_t ws_size,
                              hipStream_t stream)
{
    const float* x    = (const float*)d_in[0];
    const int*   eidx = (const int*)  d_in[1];

    const float* Wl[2]   = { (const float*)d_in[2],  (const float*)d_in[10] };
    const float* bl[2]   = { (const float*)d_in[3],  (const float*)d_in[11] };
    const float* Wr[2]   = { (const float*)d_in[4],  (const float*)d_in[12] };
    const float* br[2]   = { (const float*)d_in[5],  (const float*)d_in[13] };
    const float* att[2]  = { (const float*)d_in[6],  (const float*)d_in[14] };
    const float* bias[2] = { (const float*)d_in[7],  (const float*)d_in[15] };
    const float* gam[2]  = { (const float*)d_in[8],  (const float*)d_in[16] };
    const float* bet[2]  = { (const float*)d_in[9],  (const float*)d_in[17] };
    const float* Wout    = (const float*)d_in[18];
    const float* bout    = (const float*)d_in[19];
    const float* gout    = (const float*)d_in[20];
    const float* boutln  = (const float*)d_in[21];

    float* out = (float*)d_out;

    const size_t NF = (size_t)N_NODES * DH;
    unsigned short* xlb = (unsigned short*)d_ws;       // NF bf16
    unsigned short* xrb = xlb + NF;                    // NF bf16
    float*          h1  = (float*)(xrb + NF);          // NF fp32
    float*          h2  = h1 + NF;
    int*   csr_src = (int*)(h2 + NF);
    int*   deg     = csr_src + ETOT + 8;   // +8 pad
    int*   rowptr  = deg + N_NODES;
    int*   cursor  = rowptr + N_NODES;
    int*   bsum    = cursor + N_NODES;
    int*   boff    = bsum + NBLK;
    short* whi     = (short*)(boff + NBLK);   // 5 * 16384 shorts
    short* wlo     = whi + 5 * 16384;

    const int etBlocks   = (ETOT + 255) / 256;
    const int nodeBlocks = N_NODES / 4;
    const int gemmBlocks = (N_NODES + MTILE - 1) / MTILE;   // 391

    #define WP(i) (whi + (i) * 16384), (wlo + (i) * 16384)

    // ---- CSR (deterministic rebuild every call) ----
    hipMemsetAsync(deg, 0, N_NODES * sizeof(int), stream);
    degree_kernel       <<<etBlocks, 256, 0, stream>>>(eidx, deg);
    block_sum_kernel    <<<NBLK, 256, 0, stream>>>(deg, bsum);
    scan_partials_kernel<<<1, 256, 0, stream>>>(bsum, boff);
    rowptr_kernel       <<<NBLK, 256, 0, stream>>>(deg, boff, rowptr, cursor);
    scatter_kernel      <<<etBlocks, 256, 0, stream>>>(eidx, cursor, csr_src);

    // ---- pack all 5 weight matrices ----
    pack_w_kernel<<<320, 256, 0, stream>>>(Wl[0], Wr[0], Wl[1], Wr[1], Wout, whi, wlo);

    // ---- layer 0 ----
    gemm_mfma_kernel<<<dim3(gemmBlocks, 2), 256, 0, stream>>>(
        x, N_NODES, WP(0), bl[0], xlb, WP(1), br[0], xrb);
    gat_node_kernel<<<nodeBlocks, 256, 0, stream>>>(rowptr, deg, csr_src, xlb, xrb,
                                                    att[0], bias[0], gam[0], bet[0], h1);
    // ---- layer 1 ----
    gemm_mfma_kernel<<<dim3(gemmBlocks, 2), 256, 0, stream>>>(
        h1, N_NODES, WP(2), bl[1], xlb, WP(3), br[1], xrb);
    gat_node_kernel<<<nodeBlocks, 256, 0, stream>>>(rowptr, deg, csr_src, xlb, xrb,
                                                    att[1], bias[1], gam[1], bet[1], h2);

    // ---- output projection + fused final LayerNorm ----
    gemm1_ln_kernel<<<gemmBlocks, 256, 0, stream>>>(
        h2, N_NODES, WP(4), bout, gout, boutln, out);
}

// Round 10
// 295.274 us; speedup vs baseline: 1.3235x; 1.0382x over previous
//
#include <hip/hip_runtime.h>
#include <math.h>

#define N_NODES 50000
#define N_EDGES 800000
#define ETOT    (N_EDGES + N_NODES)
#define DH      128
#define NH      4
#define LN_EPS  1e-5f
#define NBLK    ((N_NODES + 255) / 256)   // 196 scan blocks
#define LOG2E   1.4426950408889634f

typedef __attribute__((ext_vector_type(8))) short short8;
typedef __attribute__((ext_vector_type(8))) unsigned short ushort8v;
typedef __attribute__((ext_vector_type(4))) float f32x4;
typedef __attribute__((ext_vector_type(4))) unsigned uint4v;

// ---------- fp32 -> bf16 (RNE) helpers ----------
__device__ __forceinline__ unsigned short f2bf(float f) {
    unsigned u = __float_as_uint(f);
    u += 0x7FFFu + ((u >> 16) & 1u);
    return (unsigned short)(u >> 16);
}
__device__ __forceinline__ float bf2f(unsigned short h) {
    return __uint_as_float(((unsigned)h) << 16);
}
// packed split: two fp32 -> one u32 of 2 bf16 (hi) + residual u32 (lo)
__device__ __forceinline__ void split_pair(float a, float b, unsigned& hi, unsigned& lo) {
    unsigned h;
    asm("v_cvt_pk_bf16_f32 %0, %1, %2" : "=v"(h) : "v"(a), "v"(b));
    const float ra = a - __uint_as_float(h << 16);
    const float rb = b - __uint_as_float(h & 0xffff0000u);
    unsigned l;
    asm("v_cvt_pk_bf16_f32 %0, %1, %2" : "=v"(l) : "v"(ra), "v"(rb));
    hi = h; lo = l;
}

// ---------- fast exact-GELU (A&S 7.1.26 erf, max err ~1.5e-7) ----------
__device__ __forceinline__ float gelu_exact(float x) {
    const float z  = x * 0.70710678118654752f;
    const float az = fabsf(z);
    const float tt = __builtin_amdgcn_rcpf(fmaf(0.3275911f, az, 1.f));
    float p = fmaf(1.061405429f, tt, -1.453152027f);
    p = fmaf(p, tt, 1.421413741f);
    p = fmaf(p, tt, -0.284496736f);
    p = fmaf(p, tt, 0.254829592f);
    p = p * tt;
    const float ez = exp2f(-(z * z) * LOG2E);
    float er = fmaf(-p, ez, 1.f);
    er = copysignf(er, z);
    return x * fmaf(0.5f, er, 0.5f);
}

// ========== pack 5 weight matrices into MFMA B-fragment order (hi/lo) ==========
__global__ __launch_bounds__(256) void pack_w_kernel(
    const float* __restrict__ W0, const float* __restrict__ W1,
    const float* __restrict__ W2, const float* __restrict__ W3,
    const float* __restrict__ W4,
    short* __restrict__ hi, short* __restrict__ lo)
{
    const int idx = blockIdx.x * 256 + threadIdx.x;   // 0..81919
    const int mat = idx >> 14;
    const int rem = idx & 16383;
    const int t = rem >> 12, c = (rem >> 9) & 7, l = (rem >> 3) & 63, j = rem & 7;
    const int k = t * 32 + (l >> 4) * 8 + j;
    const int n = c * 16 + (l & 15);
    const float* W = (mat == 0) ? W0 : (mat == 1) ? W1 : (mat == 2) ? W2
                   : (mat == 3) ? W3 : W4;
    const float v = W[k * DH + n];
    const unsigned short h = f2bf(v);
    hi[idx] = (short)h;
    lo[idx] = (short)f2bf(v - bf2f(h));
}

// ========== split-bf16 MFMA GEMM; bf16 outputs ==========
#define MTILE 128
__global__ __launch_bounds__(256) void gemm_mfma_kernel(
    const float* __restrict__ A, int m_rows,
    const short* __restrict__ WhiL, const short* __restrict__ WloL,
    const float* __restrict__ biasL, unsigned short* __restrict__ YL,
    const short* __restrict__ WhiR, const short* __restrict__ WloR,
    const float* __restrict__ biasR, unsigned short* __restrict__ YR)
{
    const int w    = threadIdx.x >> 6;
    const int lane = threadIdx.x & 63;
    const short* Whi  = blockIdx.y ? WhiR  : WhiL;
    const short* Wlo  = blockIdx.y ? WloR  : WloL;
    const float* bias = blockIdx.y ? biasR : biasL;
    unsigned short* Y = blockIdx.y ? YR    : YL;

    const int rows0 = blockIdx.x * MTILE + w * 32;
    const int g  = lane >> 4;
    const int rl = lane & 15;

    f32x4 acc[2][8];
    #pragma unroll
    for (int r = 0; r < 2; ++r)
        #pragma unroll
        for (int c = 0; c < 8; ++c)
            acc[r][c] = (f32x4){0.f, 0.f, 0.f, 0.f};

    for (int t = 0; t < 4; ++t) {
        short8 ahi[2], alo[2];
        #pragma unroll
        for (int r = 0; r < 2; ++r) {
            int arow = rows0 + 16 * r + rl;
            arow = (arow < m_rows) ? arow : (m_rows - 1);
            const float* ap = A + (size_t)arow * DH + t * 32 + g * 8;
            const float4 f0 = *(const float4*)ap;
            const float4 f1 = *(const float4*)(ap + 4);
            unsigned h0, l0, h1, l1, h2, l2, h3, l3;
            split_pair(f0.x, f0.y, h0, l0);
            split_pair(f0.z, f0.w, h1, l1);
            split_pair(f1.x, f1.y, h2, l2);
            split_pair(f1.z, f1.w, h3, l3);
            ahi[r] = __builtin_bit_cast(short8, (uint4v){h0, h1, h2, h3});
            alo[r] = __builtin_bit_cast(short8, (uint4v){l0, l1, l2, l3});
        }
        #pragma unroll
        for (int c = 0; c < 8; ++c) {
            const int fidx = ((t * 8 + c) * 64 + lane) * 8;
            const short8 bhi = *(const short8*)(Whi + fidx);
            const short8 blo = *(const short8*)(Wlo + fidx);
            acc[0][c] = __builtin_amdgcn_mfma_f32_16x16x32_bf16(ahi[0], bhi, acc[0][c], 0, 0, 0);
            acc[1][c] = __builtin_amdgcn_mfma_f32_16x16x32_bf16(ahi[1], bhi, acc[1][c], 0, 0, 0);
            acc[0][c] = __builtin_amdgcn_mfma_f32_16x16x32_bf16(alo[0], bhi, acc[0][c], 0, 0, 0);
            acc[1][c] = __builtin_amdgcn_mfma_f32_16x16x32_bf16(alo[1], bhi, acc[1][c], 0, 0, 0);
            acc[0][c] = __builtin_amdgcn_mfma_f32_16x16x32_bf16(ahi[0], blo, acc[0][c], 0, 0, 0);
            acc[1][c] = __builtin_amdgcn_mfma_f32_16x16x32_bf16(ahi[1], blo, acc[1][c], 0, 0, 0);
        }
    }
    #pragma unroll
    for (int c = 0; c < 8; ++c) {
        const int col = c * 16 + rl;
        const float bb = bias[col];
        #pragma unroll
        for (int r = 0; r < 2; ++r) {
            #pragma unroll
            for (int q = 0; q < 4; ++q) {
                const int row = rows0 + 16 * r + g * 4 + q;
                if (row < m_rows)
                    Y[(size_t)row * DH + col] = f2bf(acc[r][c][q] + bb);
            }
        }
    }
}

// ========== gemm1 + fused final LayerNorm: out = LN(A@W + b; g, bt) ==========
__global__ __launch_bounds__(256) void gemm1_ln_kernel(
    const float* __restrict__ A, int m_rows,
    const short* __restrict__ Whi, const short* __restrict__ Wlo,
    const float* __restrict__ bias,
    const float* __restrict__ gam, const float* __restrict__ bet,
    float* __restrict__ out)
{
    const int w    = threadIdx.x >> 6;
    const int lane = threadIdx.x & 63;
    const int rows0 = blockIdx.x * MTILE + w * 32;
    const int g  = lane >> 4;
    const int rl = lane & 15;

    f32x4 acc[2][8];
    #pragma unroll
    for (int r = 0; r < 2; ++r)
        #pragma unroll
        for (int c = 0; c < 8; ++c)
            acc[r][c] = (f32x4){0.f, 0.f, 0.f, 0.f};

    for (int t = 0; t < 4; ++t) {
        short8 ahi[2], alo[2];
        #pragma unroll
        for (int r = 0; r < 2; ++r) {
            int arow = rows0 + 16 * r + rl;
            arow = (arow < m_rows) ? arow : (m_rows - 1);
            const float* ap = A + (size_t)arow * DH + t * 32 + g * 8;
            const float4 f0 = *(const float4*)ap;
            const float4 f1 = *(const float4*)(ap + 4);
            unsigned h0, l0, h1, l1, h2, l2, h3, l3;
            split_pair(f0.x, f0.y, h0, l0);
            split_pair(f0.z, f0.w, h1, l1);
            split_pair(f1.x, f1.y, h2, l2);
            split_pair(f1.z, f1.w, h3, l3);
            ahi[r] = __builtin_bit_cast(short8, (uint4v){h0, h1, h2, h3});
            alo[r] = __builtin_bit_cast(short8, (uint4v){l0, l1, l2, l3});
        }
        #pragma unroll
        for (int c = 0; c < 8; ++c) {
            const int fidx = ((t * 8 + c) * 64 + lane) * 8;
            const short8 bh = *(const short8*)(Whi + fidx);
            const short8 bl = *(const short8*)(Wlo + fidx);
            acc[0][c] = __builtin_amdgcn_mfma_f32_16x16x32_bf16(ahi[0], bh, acc[0][c], 0, 0, 0);
            acc[1][c] = __builtin_amdgcn_mfma_f32_16x16x32_bf16(ahi[1], bh, acc[1][c], 0, 0, 0);
            acc[0][c] = __builtin_amdgcn_mfma_f32_16x16x32_bf16(alo[0], bh, acc[0][c], 0, 0, 0);
            acc[1][c] = __builtin_amdgcn_mfma_f32_16x16x32_bf16(alo[1], bh, acc[1][c], 0, 0, 0);
            acc[0][c] = __builtin_amdgcn_mfma_f32_16x16x32_bf16(ahi[0], bl, acc[0][c], 0, 0, 0);
            acc[1][c] = __builtin_amdgcn_mfma_f32_16x16x32_bf16(ahi[1], bl, acc[1][c], 0, 0, 0);
        }
    }

    float bb[8], gg[8], bt8[8];
    #pragma unroll
    for (int c = 0; c < 8; ++c) {
        const int col = c * 16 + rl;
        bb[c] = bias[col];  gg[c] = gam[col];  bt8[c] = bet[col];
    }
    #pragma unroll
    for (int r = 0; r < 2; ++r) {
        #pragma unroll
        for (int q = 0; q < 4; ++q) {
            float v[8];
            float s = 0.f, sq = 0.f;
            #pragma unroll
            for (int c = 0; c < 8; ++c) {
                v[c] = acc[r][c][q] + bb[c];
                s  += v[c];
                sq  = fmaf(v[c], v[c], sq);
            }
            #pragma unroll
            for (int off = 1; off < 16; off <<= 1) {
                s  += __shfl_xor(s,  off);
                sq += __shfl_xor(sq, off);
            }
            const float mu   = s * (1.f / 128.f);
            const float var  = sq * (1.f / 128.f) - mu * mu;
            const float rstd = rsqrtf(var + LN_EPS);
            const int row = rows0 + 16 * r + g * 4 + q;
            if (row < m_rows) {
                #pragma unroll
                for (int c = 0; c < 8; ++c)
                    out[(size_t)row * DH + c * 16 + rl] =
                        (v[c] - mu) * rstd * gg[c] + bt8[c];
            }
        }
    }
}

// ========================= CSR construction (4-edge ILP) =========================
// ETOT % 4 == 0 and N_EDGES % 4 == 0, so int4 chunks never straddle regions.
__global__ __launch_bounds__(256) void degree_kernel(
    const int* __restrict__ eidx, int* __restrict__ deg)
{
    const int base = (blockIdx.x * 256 + threadIdx.x) * 4;
    if (base < N_EDGES) {
        const int4 dv = *(const int4*)(eidx + N_EDGES + base);
        atomicAdd(&deg[dv.x], 1);
        atomicAdd(&deg[dv.y], 1);
        atomicAdd(&deg[dv.z], 1);
        atomicAdd(&deg[dv.w], 1);
    } else if (base < ETOT) {
        const int d0 = base - N_EDGES;
        atomicAdd(&deg[d0], 1);
        atomicAdd(&deg[d0 + 1], 1);
        atomicAdd(&deg[d0 + 2], 1);
        atomicAdd(&deg[d0 + 3], 1);
    }
}

__global__ __launch_bounds__(256) void block_sum_kernel(
    const int* __restrict__ deg, int* __restrict__ bsum)
{
    const int i    = blockIdx.x * 256 + threadIdx.x;
    const int lane = threadIdx.x & 63;
    const int wid  = threadIdx.x >> 6;
    int v = (i < N_NODES) ? deg[i] : 0;
    #pragma unroll
    for (int off = 32; off; off >>= 1) v += __shfl_xor(v, off);
    __shared__ int ws[4];
    if (lane == 0) ws[wid] = v;
    __syncthreads();
    if (threadIdx.x == 0) bsum[blockIdx.x] = ws[0] + ws[1] + ws[2] + ws[3];
}

__global__ __launch_bounds__(256) void scan_partials_kernel(
    const int* __restrict__ bsum, int* __restrict__ boff)
{
    const int t    = threadIdx.x;
    const int lane = t & 63;
    const int wid  = t >> 6;
    int v = (t < NBLK) ? bsum[t] : 0;
    int inc = v;
    #pragma unroll
    for (int off = 1; off < 64; off <<= 1) {
        int u = __shfl_up(inc, off);
        if (lane >= off) inc += u;
    }
    __shared__ int ws[4];
    if (lane == 63) ws[wid] = inc;
    __syncthreads();
    int add = 0;
    for (int w = 0; w < wid; ++w) add += ws[w];
    if (t < NBLK) boff[t] = add + inc - v;
}

__global__ __launch_bounds__(256) void rowptr_kernel(
    const int* __restrict__ deg, const int* __restrict__ boff,
    int* __restrict__ rowptr, int* __restrict__ cursor)
{
    const int i    = blockIdx.x * 256 + threadIdx.x;
    const int lane = threadIdx.x & 63;
    const int wid  = threadIdx.x >> 6;
    int v = (i < N_NODES) ? deg[i] : 0;
    int inc = v;
    #pragma unroll
    for (int off = 1; off < 64; off <<= 1) {
        int u = __shfl_up(inc, off);
        if (lane >= off) inc += u;
    }
    __shared__ int ws[4];
    if (lane == 63) ws[wid] = inc;
    __syncthreads();
    int add = boff[blockIdx.x];
    for (int w = 0; w < wid; ++w) add += ws[w];
    if (i < N_NODES) {
        const int ex = add + inc - v;
        rowptr[i] = ex;
        cursor[i] = ex;
    }
}

__global__ __launch_bounds__(256) void scatter_kernel(
    const int* __restrict__ eidx, int* __restrict__ cursor,
    unsigned short* __restrict__ csr_src)
{
    const int base = (blockIdx.x * 256 + threadIdx.x) * 4;
    if (base < N_EDGES) {
        const int4 sv = *(const int4*)(eidx + base);
        const int4 dv = *(const int4*)(eidx + N_EDGES + base);
        const int t0 = atomicAdd(&cursor[dv.x], 1);
        const int t1 = atomicAdd(&cursor[dv.y], 1);
        const int t2 = atomicAdd(&cursor[dv.z], 1);
        const int t3 = atomicAdd(&cursor[dv.w], 1);
        csr_src[t0] = (unsigned short)sv.x;
        csr_src[t1] = (unsigned short)sv.y;
        csr_src[t2] = (unsigned short)sv.z;
        csr_src[t3] = (unsigned short)sv.w;
    } else if (base < ETOT) {
        const int d0 = base - N_EDGES;
        const int t0 = atomicAdd(&cursor[d0], 1);
        const int t1 = atomicAdd(&cursor[d0 + 1], 1);
        const int t2 = atomicAdd(&cursor[d0 + 2], 1);
        const int t3 = atomicAdd(&cursor[d0 + 3], 1);
        csr_src[t0] = (unsigned short)d0;
        csr_src[t1] = (unsigned short)(d0 + 1);
        csr_src[t2] = (unsigned short)(d0 + 2);
        csr_src[t3] = (unsigned short)(d0 + 3);
    }
}

// ====== fused per-node GAT: 16 lanes/edge (8 bf16 ch), prefetch, no-max softmax ======
__global__ __launch_bounds__(256) void gat_node_kernel(
    const int* __restrict__ rowptr, const int* __restrict__ deg,
    const unsigned short* __restrict__ csr_src,
    const unsigned short* __restrict__ xlb, const unsigned short* __restrict__ xrb,
    const float* __restrict__ att, const float* __restrict__ bias,
    const float* __restrict__ gam, const float* __restrict__ bet,
    float* __restrict__ out)
{
    const int n    = blockIdx.x * 4 + (threadIdx.x >> 6);
    const int lane = threadIdx.x & 63;
    if (n >= N_NODES) return;
    const int q  = lane >> 4;       // edge slot 0..3
    const int r  = lane & 15;       // channel group
    const int c0 = r * 8;

    const ushort8v ur = *(const ushort8v*)(xrb + (size_t)n * DH + c0);
    float xrv[8];
    #pragma unroll
    for (int j = 0; j < 8; ++j) xrv[j] = bf2f(ur[j]);

    float a6[8], a4[8];
    #pragma unroll
    for (int j = 0; j < 8; ++j) {
        const float a = att[c0 + j];
        a6[j] = a * (0.6f * LOG2E);
        a4[j] = a * (0.4f * LOG2E);
    }

    float dsum = 0.f;
    float p[8];
    #pragma unroll
    for (int j = 0; j < 8; ++j) p[j] = 0.f;

    const int beg = rowptr[n];
    const int end = beg + deg[n];

    int e = beg;
    bool vcur = (e + q) < end;
    int s = vcur ? (int)csr_src[e + q] : 0;
    ushort8v u = *(const ushort8v*)(xlb + (size_t)s * DH + c0);

    while (e < end) {
        const int en = e + 4;
        ushort8v unext = u;
        bool vnext = false;
        if (en < end) {   // wave-uniform
            vnext = (en + q) < end;
            const int sn = vnext ? (int)csr_src[en + q] : 0;
            unext = *(const ushort8v*)(xlb + (size_t)sn * DH + c0);
        }
        float x[8];
        #pragma unroll
        for (int j = 0; j < 8; ++j) x[j] = bf2f(u[j]);
        float l = 0.f;
        #pragma unroll
        for (int j = 0; j < 8; ++j) {
            const float t = x[j] + xrv[j];
            l = fmaf(a6[j], t, fmaf(a4[j], fabsf(t), l));
        }
        l += __shfl_xor(l, 1);
        l += __shfl_xor(l, 2);
        l = vcur ? l : -INFINITY;
        const float w = exp2f(l);
        dsum += w;
        #pragma unroll
        for (int j = 0; j < 8; ++j) p[j] = fmaf(x[j], w, p[j]);

        u = unext; vcur = vnext; e = en;
    }

    dsum += __shfl_xor(dsum, 16);
    dsum += __shfl_xor(dsum, 32);
    #pragma unroll
    for (int j = 0; j < 8; ++j) {
        p[j] += __shfl_xor(p[j], 16);
        p[j] += __shfl_xor(p[j], 32);
    }

    const float inv = 1.f / dsum;
    float v[8];
    float s2 = 0.f, sq = 0.f;
    #pragma unroll
    for (int j = 0; j < 8; ++j) {
        v[j] = p[j] * inv + bias[c0 + j];
        s2 += v[j];
        sq  = fmaf(v[j], v[j], sq);
    }
    #pragma unroll
    for (int off = 1; off < 16; off <<= 1) {
        s2 += __shfl_xor(s2, off);
        sq += __shfl_xor(sq, off);
    }
    const float mu   = s2 * (1.f / 128.f);
    const float var  = sq * (1.f / 128.f) - mu * mu;
    const float rstd = rsqrtf(var + LN_EPS);

    if (q == 0) {
        float y[8];
        #pragma unroll
        for (int j = 0; j < 8; ++j)
            y[j] = gelu_exact((v[j] - mu) * rstd * gam[c0 + j] + bet[c0 + j]);
        float4 y0 = {y[0], y[1], y[2], y[3]};
        float4 y1 = {y[4], y[5], y[6], y[7]};
        *(float4*)(out + (size_t)n * DH + c0)     = y0;
        *(float4*)(out + (size_t)n * DH + c0 + 4) = y1;
    }
}

extern "C" void kernel_launch(void* const* d_in, const int* in_sizes, int n_in,
                              void* d_out, int out_size, void* d_ws, size_t ws_size,
                              hipStream_t stream)
{
    const float* x    = (const float*)d_in[0];
    const int*   eidx = (const int*)  d_in[1];

    const float* Wl[2]   = { (const float*)d_in[2],  (const float*)d_in[10] };
    const float* bl[2]   = { (const float*)d_in[3],  (const float*)d_in[11] };
    const float* Wr[2]   = { (const float*)d_in[4],  (const float*)d_in[12] };
    const float* br[2]   = { (const float*)d_in[5],  (const float*)d_in[13] };
    const float* att[2]  = { (const float*)d_in[6],  (const float*)d_in[14] };
    const float* bias[2] = { (const float*)d_in[7],  (const float*)d_in[15] };
    const float* gam[2]  = { (const float*)d_in[8],  (const float*)d_in[16] };
    const float* bet[2]  = { (const float*)d_in[9],  (const float*)d_in[17] };
    const float* Wout    = (const float*)d_in[18];
    const float* bout    = (const float*)d_in[19];
    const float* gout    = (const float*)d_in[20];
    const float* boutln  = (const float*)d_in[21];

    float* out = (float*)d_out;

    const size_t NF = (size_t)N_NODES * DH;
    unsigned short* xlb = (unsigned short*)d_ws;       // NF bf16
    unsigned short* xrb = xlb + NF;                    // NF bf16
    float*          h1  = (float*)(xrb + NF);          // NF fp32
    float*          h2  = h1 + NF;
    unsigned short* csr_src = (unsigned short*)(h2 + NF);   // ETOT u16
    int*   deg     = (int*)(csr_src + ETOT + 16);
    int*   rowptr  = deg + N_NODES;
    int*   cursor  = rowptr + N_NODES;
    int*   bsum    = cursor + N_NODES;
    int*   boff    = bsum + NBLK;
    short* whi     = (short*)(boff + NBLK);   // 5 * 16384 shorts
    short* wlo     = whi + 5 * 16384;

    const int csrBlocks  = (ETOT / 4 + 255) / 256;   // 831
    const int nodeBlocks = N_NODES / 4;
    const int gemmBlocks = (N_NODES + MTILE - 1) / MTILE;   // 391

    #define WP(i) (whi + (i) * 16384), (wlo + (i) * 16384)

    // ---- CSR (deterministic rebuild every call) ----
    hipMemsetAsync(deg, 0, N_NODES * sizeof(int), stream);
    degree_kernel       <<<csrBlocks, 256, 0, stream>>>(eidx, deg);
    block_sum_kernel    <<<NBLK, 256, 0, stream>>>(deg, bsum);
    scan_partials_kernel<<<1, 256, 0, stream>>>(bsum, boff);
    rowptr_kernel       <<<NBLK, 256, 0, stream>>>(deg, boff, rowptr, cursor);
    scatter_kernel      <<<csrBlocks, 256, 0, stream>>>(eidx, cursor, csr_src);

    // ---- pack all 5 weight matrices ----
    pack_w_kernel<<<320, 256, 0, stream>>>(Wl[0], Wr[0], Wl[1], Wr[1], Wout, whi, wlo);

    // ---- layer 0 ----
    gemm_mfma_kernel<<<dim3(gemmBlocks, 2), 256, 0, stream>>>(
        x, N_NODES, WP(0), bl[0], xlb, WP(1), br[0], xrb);
    gat_node_kernel<<<nodeBlocks, 256, 0, stream>>>(rowptr, deg, csr_src, xlb, xrb,
                                                    att[0], bias[0], gam[0], bet[0], h1);
    // ---- layer 1 ----
    gemm_mfma_kernel<<<dim3(gemmBlocks, 2), 256, 0, stream>>>(
        h1, N_NODES, WP(2), bl[1], xlb, WP(3), br[1], xrb);
    gat_node_kernel<<<nodeBlocks, 256, 0, stream>>>(rowptr, deg, csr_src, xlb, xrb,
                                                    att[1], bias[1], gam[1], bet[1], h2);

    // ---- output projection + fused final LayerNorm ----
    gemm1_ln_kernel<<<gemmBlocks, 256, 0, stream>>>(
        h2, N_NODES, WP(4), bout, gout, boutln, out);
}